// Round 12
// baseline (348.126 us; speedup 1.0000x reference)
//
#include <hip/hip_runtime.h>
#include <math.h>

#define N_NODES 20000
#define N_EDGES 320000
#define MUL 64
#define NUM_BASIS 8
#define HID 64
#define NSPEC 4

#define LIN_NORM     0.125f          // 1/sqrt(64)
#define INV_SQRT8    0.3535533906f   // 1/sqrt(8)
#define LIN2_NORM    0.08838834765f  // 1/sqrt(128)
#define SC_NORM      0.0625f         // 1/sqrt(64*4)
#define INV_NEIGH    0.0625f         // 1/16
#define INV_SQRT3    0.5773502692f
#define SILU_NORM    1.679177f

typedef __attribute__((ext_vector_type(8))) short bf16x8;
typedef __attribute__((ext_vector_type(4))) float f32x4;

__device__ __forceinline__ float silu_n(float x) {
    float s = 1.0f / (1.0f + __expf(-x));
    return x * s * SILU_NORM;
}

__device__ __forceinline__ float bcast(float x, int l) {
    return __uint_as_float(__builtin_amdgcn_readlane(__float_as_uint(x), l));
}
__device__ __forceinline__ int bcast_i(int x, int l) {
    return __builtin_amdgcn_readlane(x, l);
}

// fp32 -> bf16 with round-to-nearest-even
__device__ __forceinline__ unsigned short f2bf(float x) {
    unsigned int u = __float_as_uint(x);
    unsigned int r = (u + 0x7fffu + ((u >> 16) & 1u)) >> 16;
    return (unsigned short)r;
}

// packed 2x bf16 convert: D[15:0]=bf16(lo), D[31:16]=bf16(hi)
__device__ __forceinline__ unsigned int cvtpk(float lo, float hi) {
    unsigned int r;
    asm("v_cvt_pk_bf16_f32 %0, %1, %2" : "=v"(r) : "v"(lo), "v"(hi));
    return r;
}

__device__ __forceinline__ bf16x8 cvt8(float f0, float f1, float f2, float f3,
                                       float f4, float f5, float f6, float f7) {
    union { unsigned int u[4]; bf16x8 v; } r;
    r.u[0] = cvtpk(f0, f1);
    r.u[1] = cvtpk(f2, f3);
    r.u[2] = cvtpk(f4, f5);
    r.u[3] = cvtpk(f6, f7);
    return r.v;
}

// ---------------------------------------------------------------------------
// k_pre: blocks 0-50 = weight swizzle (13056 threads); blocks 51+ = grid-stride
// zero of s_agg..v_agg (N*512 floats, float4) + counts.
// ---------------------------------------------------------------------------
#define WPREP_BLOCKS 51
__global__ __launch_bounds__(256) void k_pre(
    const float* __restrict__ W1, const float* __restrict__ W2,
    const float* __restrict__ Wl2s, const float* __restrict__ Wl2v,
    const float* __restrict__ Wscs, const float* __restrict__ Wscv,
    const float* __restrict__ W0,
    const float* __restrict__ Wl1s, const float* __restrict__ Wl1v,
    unsigned short* __restrict__ w1f, unsigned short* __restrict__ w2f,
    unsigned short* __restrict__ bsf, unsigned short* __restrict__ bvf,
    unsigned short* __restrict__ w0f,
    unsigned short* __restrict__ l1sf, unsigned short* __restrict__ l1vf,
    float4* __restrict__ agg4, int* __restrict__ counts)
{
    if (blockIdx.x >= WPREP_BLOCKS) {
        int idx = (blockIdx.x - WPREP_BLOCKS) * 256 + threadIdx.x;
        int nthr = (gridDim.x - WPREP_BLOCKS) * 256;
        const size_t total4 = (size_t)N_NODES * 128;   // N*512 floats
        float4 z = {0.f, 0.f, 0.f, 0.f};
        for (size_t i = idx; i < total4; i += nthr) agg4[i] = z;
        if (idx < N_NODES) counts[idx] = 0;
        return;
    }
    int t = blockIdx.x * 256 + threadIdx.x;
    if (t < 512) {                       // W1: 8 frags (kt*4+nt)
        int f = t >> 6, lane = t & 63;
        int kt = f >> 2, nt = f & 3, q = lane >> 4, c = lane & 15;
        #pragma unroll
        for (int j = 0; j < 8; ++j) {
            int k = kt * 32 + q * 8 + j;
            int n = nt * 16 + c;
            w1f[(size_t)t * 8 + j] = f2bf(W1[k * 64 + n]);
        }
    } else if (t < 2560) {               // W2: 32 frags (kt*16+nt)
        int tt = t - 512;
        int f = tt >> 6, lane = tt & 63;
        int kt = f >> 4, nt = f & 15, q = lane >> 4, c = lane & 15;
        #pragma unroll
        for (int j = 0; j < 8; ++j) {
            int k = kt * 32 + q * 8 + j;
            int n = nt * 16 + c;
            w2f[(size_t)tt * 8 + j] = f2bf(W2[k * 256 + n]);
        }
    } else if (t < 4608) {               // bs_lin: 32 frags, 128x128
        int tt = t - 2560;
        int f = tt >> 6, lane = tt & 63;
        int kt = f >> 3, nt = f & 7, q = lane >> 4, c = lane & 15;
        #pragma unroll
        for (int j = 0; j < 8; ++j) {
            int k = kt * 32 + q * 8 + j;
            int n = nt * 16 + c;
            bsf[(size_t)tt * 8 + j] = f2bf(Wl2s[k * 128 + n] * LIN2_NORM);
        }
    } else if (t < 8704) {               // bs_sc: 64 frags (v*16+kt*8+nt), 64x128 per v
        int tt = t - 4608;
        int f = tt >> 6, lane = tt & 63;
        int v = f >> 4, g = f & 15;
        int kt = g >> 3, nt = g & 7, q = lane >> 4, c = lane & 15;
        #pragma unroll
        for (int j = 0; j < 8; ++j) {
            int u = kt * 32 + q * 8 + j;          // u < 64
            int n = nt * 16 + c;
            bsf[(size_t)(2048 + tt) * 8 + j] = f2bf(Wscs[(u * 4 + v) * 128 + n] * SC_NORM);
        }
    } else if (t < 9728) {               // bv_lin: 16 frags, 128x64
        int tt = t - 8704;
        int f = tt >> 6, lane = tt & 63;
        int kt = f >> 2, nt = f & 3, q = lane >> 4, c = lane & 15;
        #pragma unroll
        for (int j = 0; j < 8; ++j) {
            int k = kt * 32 + q * 8 + j;
            int n = nt * 16 + c;
            bvf[(size_t)tt * 8 + j] = f2bf(Wl2v[k * 64 + n] * LIN2_NORM);
        }
    } else if (t < 11776) {              // bv_sc: 32 frags (v*8+kt*4+nt), 64x64 per v
        int tt = t - 9728;
        int f = tt >> 6, lane = tt & 63;
        int v = f >> 3, g = f & 7;
        int kt = g >> 2, nt = g & 3, q = lane >> 4, c = lane & 15;
        #pragma unroll
        for (int j = 0; j < 8; ++j) {
            int u = kt * 32 + q * 8 + j;          // u < 64
            int n = nt * 16 + c;
            bvf[(size_t)(1024 + tt) * 8 + j] = f2bf(Wscv[(u * 4 + v) * 64 + n] * SC_NORM);
        }
    } else if (t < 12032) {              // w0f: 4 frags (nt), K=8 padded to 32
        int tt = t - 11776;
        int f = tt >> 6, lane = tt & 63;
        int q = lane >> 4, c = lane & 15;
        #pragma unroll
        for (int j = 0; j < 8; ++j) {
            int k = q * 8 + j;
            int n = f * 16 + c;
            w0f[(size_t)tt * 8 + j] =
                (k < 8) ? f2bf(W0[k * 64 + n] * INV_SQRT8) : (unsigned short)0;
        }
    } else if (t < 12544) {              // l1sf: 8 frags (kt*4+nt), LIN_NORM folded
        int tt = t - 12032;
        int f = tt >> 6, lane = tt & 63;
        int kt = f >> 2, nt = f & 3, q = lane >> 4, c = lane & 15;
        #pragma unroll
        for (int j = 0; j < 8; ++j) {
            int k = kt * 32 + q * 8 + j;
            int n = nt * 16 + c;
            l1sf[(size_t)tt * 8 + j] = f2bf(Wl1s[k * 64 + n] * LIN_NORM);
        }
    } else if (t < 13056) {              // l1vf: 8 frags (kt*4+nt), LIN_NORM folded
        int tt = t - 12544;
        int f = tt >> 6, lane = tt & 63;
        int kt = f >> 2, nt = f & 3, q = lane >> 4, c = lane & 15;
        #pragma unroll
        for (int j = 0; j < 8; ++j) {
            int k = kt * 32 + q * 8 + j;
            int n = nt * 16 + c;
            l1vf[(size_t)tt * 8 + j] = f2bf(Wl1v[k * 64 + n] * LIN_NORM);
        }
    }
}

// ---------------------------------------------------------------------------
// CSR build: histogram -> 1-block scan (unchanged bodies)
// ---------------------------------------------------------------------------
__global__ __launch_bounds__(256) void k_hist(const int* __restrict__ edst,
                                              int* __restrict__ counts)
{
    int e = blockIdx.x * blockDim.x + threadIdx.x;
    if (e < N_EDGES) atomicAdd(&counts[edst[e]], 1);
}

#define SCAN_T 1024
__global__ __launch_bounds__(SCAN_T) void k_scan(const int* __restrict__ counts,
                                                 int* __restrict__ cursor)
{
    __shared__ int part[SCAN_T];
    int t = threadIdx.x;
    const int CH = (N_NODES + SCAN_T - 1) / SCAN_T;   // 20
    int b0 = t * CH;
    int s = 0;
    for (int i = 0; i < CH; ++i) {
        int idx = b0 + i;
        if (idx < N_NODES) s += counts[idx];
    }
    part[t] = s;
    __syncthreads();
    for (int off = 1; off < SCAN_T; off <<= 1) {
        int v = (t >= off) ? part[t - off] : 0;
        __syncthreads();
        part[t] += v;
        __syncthreads();
    }
    int run = (t == 0) ? 0 : part[t - 1];
    for (int i = 0; i < CH; ++i) {
        int idx = b0 + i;
        if (idx < N_NODES) {
            cursor[idx] = run;
            run += counts[idx];
        }
    }
}

// ---------------------------------------------------------------------------
// k_fill_lin1: blocks 0-1249 = edge-payload scatter; blocks 1250+ = node lin1
// on MFMA (4-way wave split). Bodies unchanged.
// ---------------------------------------------------------------------------
#define FILL_BLOCKS 1250
__global__ __launch_bounds__(256) void k_fill_lin1(
    const int* __restrict__ edst, const int* __restrict__ esrc,
    const float* __restrict__ sh, const float* __restrict__ emb,
    int* __restrict__ cursor,
    int* __restrict__ dlist, int* __restrict__ slist,
    float4* __restrict__ ysort, float4* __restrict__ esort,
    const float* __restrict__ ns, const float* __restrict__ nv,
    const unsigned short* __restrict__ l1sf, const unsigned short* __restrict__ l1vf,
    float* __restrict__ s_out, float* __restrict__ v_out)
{
    if (blockIdx.x < FILL_BLOCKS) {
        int e = blockIdx.x * blockDim.x + threadIdx.x;
        if (e < N_EDGES) {
            int d = edst[e];
            int pos = atomicAdd(&cursor[d], 1);
            dlist[pos] = d;
            slist[pos] = esrc[e];
            ysort[pos] = ((const float4*)sh)[e];
            esort[(size_t)pos * 2]     = ((const float4*)emb)[(size_t)e * 2];
            esort[(size_t)pos * 2 + 1] = ((const float4*)emb)[(size_t)e * 2 + 1];
        }
        return;
    }
    const size_t NV = (size_t)N_NODES * 64;
    int lane = threadIdx.x & 63;
    int gwave = ((blockIdx.x - FILL_BLOCKS) * 256 + threadIdx.x) >> 6;
    int part = __builtin_amdgcn_readfirstlane(gwave & 3);
    int n0 = __builtin_amdgcn_readfirstlane((gwave >> 2) * 16);
    if (n0 >= N_NODES) return;
    int q = lane >> 4, c = lane & 15;
    int node = n0 + c;

    if (part == 0) {
        f32x4 Ds[4];
        #pragma unroll
        for (int nt = 0; nt < 4; ++nt) Ds[nt] = (f32x4){0.f, 0.f, 0.f, 0.f};
        #pragma unroll
        for (int kt = 0; kt < 2; ++kt) {
            const float* ap = ns + (size_t)node * 64 + kt * 32 + q * 8;
            float4 a0 = *(const float4*)ap;
            float4 a1 = *(const float4*)(ap + 4);
            bf16x8 A = cvt8(a0.x, a0.y, a0.z, a0.w, a1.x, a1.y, a1.z, a1.w);
            #pragma unroll
            for (int nt = 0; nt < 4; ++nt) {
                bf16x8 B = *(const bf16x8*)(l1sf + (size_t)((kt * 4 + nt) * 64 + lane) * 8);
                Ds[nt] = __builtin_amdgcn_mfma_f32_16x16x32_bf16(A, B, Ds[nt], 0, 0, 0);
            }
        }
        #pragma unroll
        for (int nt = 0; nt < 4; ++nt)
            #pragma unroll
            for (int r = 0; r < 4; ++r)
                s_out[(size_t)(n0 + q * 4 + r) * 64 + nt * 16 + c] = Ds[nt][r];
    } else {
        int p = part - 1;
        f32x4 Dv[4];
        #pragma unroll
        for (int nt = 0; nt < 4; ++nt) Dv[nt] = (f32x4){0.f, 0.f, 0.f, 0.f};
        #pragma unroll
        for (int kt = 0; kt < 2; ++kt) {
            float f[8];
            #pragma unroll
            for (int j = 0; j < 8; ++j)
                f[j] = nv[(size_t)node * 192 + (size_t)(kt * 32 + q * 8 + j) * 3 + p];
            bf16x8 A = cvt8(f[0], f[1], f[2], f[3], f[4], f[5], f[6], f[7]);
            #pragma unroll
            for (int nt = 0; nt < 4; ++nt) {
                bf16x8 B = *(const bf16x8*)(l1vf + (size_t)((kt * 4 + nt) * 64 + lane) * 8);
                Dv[nt] = __builtin_amdgcn_mfma_f32_16x16x32_bf16(A, B, Dv[nt], 0, 0, 0);
            }
        }
        #pragma unroll
        for (int nt = 0; nt < 4; ++nt)
            #pragma unroll
            for (int r = 0; r < 4; ++r)
                v_out[p * NV + (size_t)(n0 + q * 4 + r) * 64 + nt * 16 + c] = Dv[nt][r];
    }
}

// ---------------------------------------------------------------------------
// Kernel B (FUSED): edge MLP + TP + run-merge scatter.
// ONLY change vs R10: scatter stages all 16 tile edges at once (64 VMEM +
// 32 LDS loads in flight) instead of 2x8 — doubles gather latency overlap.
// ---------------------------------------------------------------------------
__global__ __launch_bounds__(256) void k_edge_fused(
    const float* __restrict__ esort,
    const unsigned short* __restrict__ w0f,
    const unsigned short* __restrict__ w1f, const unsigned short* __restrict__ w2f,
    const int* __restrict__ slist, const int* __restrict__ dlist,
    const float* __restrict__ ysort,
    const float* __restrict__ s_in, const float* __restrict__ v_in,
    float* __restrict__ s_agg, float* __restrict__ v_agg)
{
    const size_t NP2 = (size_t)N_NODES * 128;
    const size_t NV  = (size_t)N_NODES * 64;

    __shared__ unsigned short h0t[4 * 16 * 72];
    __shared__ unsigned short h1t[4 * 16 * 72];
    __shared__ unsigned int   wl1[4 * 16 * 66];   // packed (wA,wB) per wave
    __shared__ unsigned int   wl2[4 * 16 * 66];   // packed (wC,wD)

    int lane = threadIdx.x & 63;
    int wid  = threadIdx.x >> 6;
    int q = lane >> 4;
    int c = lane & 15;
    int lbase = __builtin_amdgcn_readfirstlane(blockIdx.x * 256 + wid * 64);
    unsigned short* myh0 = h0t + wid * (16 * 72);
    unsigned short* myh1 = h1t + wid * (16 * 72);
    unsigned int*   myw1 = wl1 + wid * (16 * 66);
    unsigned int*   myw2 = wl2 + wid * (16 * 66);

    int srcv = slist[lbase + lane];
    int dstv = dlist[lbase + lane];
    float4 y4 = ((const float4*)ysort)[lbase + lane];

    bf16x8 B0[4];
    #pragma unroll
    for (int f = 0; f < 4; ++f)
        B0[f] = *(const bf16x8*)(w0f + (size_t)(f * 64 + lane) * 8);
    bf16x8 B1[2][4];
    #pragma unroll
    for (int f = 0; f < 8; ++f)
        B1[f >> 2][f & 3] = *(const bf16x8*)(w1f + (size_t)(f * 64 + lane) * 8);

    const float4* e4 = (const float4*)esort;
    const float WS  = 0.125f * INV_NEIGH;
    const float WSD = WS * INV_SQRT3;

    float accA = 0.f, aB0 = 0.f, aB1 = 0.f, aB2 = 0.f;
    float accD = 0.f, aC0 = 0.f, aC1 = 0.f, aC2 = 0.f;
    int cur = bcast_i(dstv, 0);

    #pragma unroll 1
    for (int mt = 0; mt < 4; ++mt) {
        int tb16 = mt * 16;

        // ======== MLP phase (all MFMA, lgkm-only waits) ========
        float4 ea = {0.f, 0.f, 0.f, 0.f}, eb = {0.f, 0.f, 0.f, 0.f};
        if (q == 0) {
            ea = e4[(size_t)(lbase + tb16 + c) * 2];
            eb = e4[(size_t)(lbase + tb16 + c) * 2 + 1];
        }
        bf16x8 Ae = cvt8(ea.x, ea.y, ea.z, ea.w, eb.x, eb.y, eb.z, eb.w);
        f32x4 D0[4];
        #pragma unroll
        for (int nt = 0; nt < 4; ++nt) {
            f32x4 z = {0.f, 0.f, 0.f, 0.f};
            D0[nt] = __builtin_amdgcn_mfma_f32_16x16x32_bf16(Ae, B0[nt], z, 0, 0, 0);
        }
        #pragma unroll
        for (int nt = 0; nt < 4; ++nt)
            #pragma unroll
            for (int r = 0; r < 4; ++r)
                myh0[(q * 4 + r) * 72 + nt * 16 + c] = f2bf(silu_n(D0[nt][r]));
        __builtin_amdgcn_s_waitcnt(0xC07F);   // lgkmcnt(0) ONLY
        bf16x8 A0[2];
        #pragma unroll
        for (int kt = 0; kt < 2; ++kt)
            A0[kt] = *(const bf16x8*)(myh0 + c * 72 + kt * 32 + q * 8);

        f32x4 D1[4];
        #pragma unroll
        for (int nt = 0; nt < 4; ++nt) {
            f32x4 z = {0.f, 0.f, 0.f, 0.f};
            D1[nt] = __builtin_amdgcn_mfma_f32_16x16x32_bf16(A0[0], B1[0][nt], z, 0, 0, 0);
            D1[nt] = __builtin_amdgcn_mfma_f32_16x16x32_bf16(A0[1], B1[1][nt], D1[nt], 0, 0, 0);
        }
        #pragma unroll
        for (int nt = 0; nt < 4; ++nt)
            #pragma unroll
            for (int r = 0; r < 4; ++r)
                myh1[(q * 4 + r) * 72 + nt * 16 + c] = f2bf(silu_n(D1[nt][r] * 0.125f));
        __builtin_amdgcn_s_waitcnt(0xC07F);   // lgkmcnt(0) ONLY
        bf16x8 A1[2];
        #pragma unroll
        for (int kt = 0; kt < 2; ++kt)
            A1[kt] = *(const bf16x8*)(myh1 + c * 72 + kt * 32 + q * 8);

        #pragma unroll
        for (int half = 0; half < 2; ++half) {
            int ga = half * 2, gb = half * 2 + 1;
            f32x4 Da[4], Db[4];
            #pragma unroll
            for (int ntl = 0; ntl < 4; ++ntl) {
                bf16x8 b0 = *(const bf16x8*)(w2f + (size_t)((ga * 4 + ntl) * 64 + lane) * 8);
                bf16x8 b1 = *(const bf16x8*)(w2f + (size_t)((16 + ga * 4 + ntl) * 64 + lane) * 8);
                f32x4 z = {0.f, 0.f, 0.f, 0.f};
                Da[ntl] = __builtin_amdgcn_mfma_f32_16x16x32_bf16(A1[0], b0, z, 0, 0, 0);
                Da[ntl] = __builtin_amdgcn_mfma_f32_16x16x32_bf16(A1[1], b1, Da[ntl], 0, 0, 0);
            }
            #pragma unroll
            for (int ntl = 0; ntl < 4; ++ntl) {
                bf16x8 b0 = *(const bf16x8*)(w2f + (size_t)((gb * 4 + ntl) * 64 + lane) * 8);
                bf16x8 b1 = *(const bf16x8*)(w2f + (size_t)((16 + gb * 4 + ntl) * 64 + lane) * 8);
                f32x4 z = {0.f, 0.f, 0.f, 0.f};
                Db[ntl] = __builtin_amdgcn_mfma_f32_16x16x32_bf16(A1[0], b0, z, 0, 0, 0);
                Db[ntl] = __builtin_amdgcn_mfma_f32_16x16x32_bf16(A1[1], b1, Db[ntl], 0, 0, 0);
            }
            float sb = half ? WSD : WS;
            unsigned int* pp = half ? myw2 : myw1;
            #pragma unroll
            for (int ntl = 0; ntl < 4; ++ntl)
                #pragma unroll
                for (int r = 0; r < 4; ++r)
                    pp[(q * 4 + r) * 66 + ntl * 16 + c] = cvtpk(Da[ntl][r] * WS, Db[ntl][r] * sb);
        }
        __builtin_amdgcn_s_waitcnt(0xC07F);   // drain LDS writes before reads

        // ======== scatter phase: stage ALL 16 edges, then accumulate ========
        {
            float se[16], v0s[16], v1s[16], v2s[16];
            unsigned int wab[16], wcd[16];
            #pragma unroll
            for (int i = 0; i < 16; ++i) {
                int src = bcast_i(srcv, tb16 + i);
                wab[i] = myw1[i * 66 + lane];
                wcd[i] = myw2[i * 66 + lane];
                se[i]  = s_in[(size_t)src * 64 + lane];
                v0s[i] = v_in[0 * NV + (size_t)src * 64 + lane];
                v1s[i] = v_in[1 * NV + (size_t)src * 64 + lane];
                v2s[i] = v_in[2 * NV + (size_t)src * 64 + lane];
            }
            #pragma unroll
            for (int i = 0; i < 16; ++i) {
                int e = tb16 + i;
                int dst = bcast_i(dstv, e);
                float y0 = bcast(y4.x, e), yx = bcast(y4.y, e);
                float yy = bcast(y4.z, e), yz = bcast(y4.w, e);
                if (dst != cur) {
                    size_t db = (size_t)cur * 128;
                    unsafeAtomicAdd(&s_agg[db + lane], accA);
                    unsafeAtomicAdd(&s_agg[db + 64 + lane], accD);
                    unsafeAtomicAdd(&v_agg[0 * NP2 + db + lane], aB0);
                    unsafeAtomicAdd(&v_agg[1 * NP2 + db + lane], aB1);
                    unsafeAtomicAdd(&v_agg[2 * NP2 + db + lane], aB2);
                    unsafeAtomicAdd(&v_agg[0 * NP2 + db + 64 + lane], aC0);
                    unsafeAtomicAdd(&v_agg[1 * NP2 + db + 64 + lane], aC1);
                    unsafeAtomicAdd(&v_agg[2 * NP2 + db + 64 + lane], aC2);
                    accA = aB0 = aB1 = aB2 = 0.f;
                    accD = aC0 = aC1 = aC2 = 0.f;
                    cur = dst;
                }
                float wA = __uint_as_float(wab[i] << 16);
                float wB = __uint_as_float(wab[i] & 0xffff0000u);
                float wC = __uint_as_float(wcd[i] << 16);
                float wD = __uint_as_float(wcd[i] & 0xffff0000u);  // INV_SQRT3 folded
                accA = fmaf(wA, se[i] * y0, accA);
                float bB = wB * se[i];
                aB0 = fmaf(bB, yx, aB0);
                aB1 = fmaf(bB, yy, aB1);
                aB2 = fmaf(bB, yz, aB2);
                float dot = v0s[i] * yx + v1s[i] * yy + v2s[i] * yz;
                accD = fmaf(wD, dot, accD);
                float bC = wC * y0;
                aC0 = fmaf(bC, v0s[i], aC0);
                aC1 = fmaf(bC, v1s[i], aC1);
                aC2 = fmaf(bC, v2s[i], aC2);
            }
        }
    }
    // final flush
    {
        size_t db = (size_t)cur * 128;
        unsafeAtomicAdd(&s_agg[db + lane], accA);
        unsafeAtomicAdd(&s_agg[db + 64 + lane], accD);
        unsafeAtomicAdd(&v_agg[0 * NP2 + db + lane], aB0);
        unsafeAtomicAdd(&v_agg[1 * NP2 + db + lane], aB1);
        unsafeAtomicAdd(&v_agg[2 * NP2 + db + lane], aB2);
        unsafeAtomicAdd(&v_agg[0 * NP2 + db + 64 + lane], aC0);
        unsafeAtomicAdd(&v_agg[1 * NP2 + db + 64 + lane], aC1);
        unsafeAtomicAdd(&v_agg[2 * NP2 + db + 64 + lane], aC2);
    }
}

// ---------------------------------------------------------------------------
// Kernel C1: scalar epilogue — out_s + gate -> global gbuf. (unchanged)
// ---------------------------------------------------------------------------
__global__ __launch_bounds__(256) void k_node_out_s(
    const float* __restrict__ ns, const float* __restrict__ na,
    const unsigned short* __restrict__ bsf,
    const float* __restrict__ s_agg,
    float* __restrict__ out, float* __restrict__ gbuf)
{
    int lane = threadIdx.x & 63;
    int wtile = (blockIdx.x * blockDim.x + threadIdx.x) >> 6;
    int n0 = __builtin_amdgcn_readfirstlane(wtile * 16);
    if (n0 >= N_NODES) return;
    int q = lane >> 4, c = lane & 15;
    int node = n0 + c;

    float pa[4];
    #pragma unroll
    for (int v = 0; v < 4; ++v) pa[v] = na[(size_t)node * 4 + v];

    f32x4 Ds[8];
    #pragma unroll
    for (int nt = 0; nt < 8; ++nt) Ds[nt] = (f32x4){0.f, 0.f, 0.f, 0.f};

    #pragma unroll
    for (int kt = 0; kt < 4; ++kt) {
        const float* ap = s_agg + (size_t)node * 128 + kt * 32 + q * 8;
        float4 a0 = *(const float4*)ap;
        float4 a1 = *(const float4*)(ap + 4);
        bf16x8 A;
        A[0] = (short)f2bf(a0.x); A[1] = (short)f2bf(a0.y);
        A[2] = (short)f2bf(a0.z); A[3] = (short)f2bf(a0.w);
        A[4] = (short)f2bf(a1.x); A[5] = (short)f2bf(a1.y);
        A[6] = (short)f2bf(a1.z); A[7] = (short)f2bf(a1.w);
        #pragma unroll
        for (int nt = 0; nt < 8; ++nt) {
            bf16x8 B = *(const bf16x8*)(bsf + (size_t)((kt * 8 + nt) * 64 + lane) * 8);
            Ds[nt] = __builtin_amdgcn_mfma_f32_16x16x32_bf16(A, B, Ds[nt], 0, 0, 0);
        }
    }
    {
        const float* np_ = ns + (size_t)node * 64 + q * 8;
        float4 n00 = *(const float4*)np_;
        float4 n01 = *(const float4*)(np_ + 4);
        float4 n10 = *(const float4*)(np_ + 32);
        float4 n11 = *(const float4*)(np_ + 36);
        float nsr[16] = {n00.x, n00.y, n00.z, n00.w, n01.x, n01.y, n01.z, n01.w,
                         n10.x, n10.y, n10.z, n10.w, n11.x, n11.y, n11.z, n11.w};
        #pragma unroll
        for (int v = 0; v < 4; ++v) {
            float sv = pa[v];
            #pragma unroll
            for (int kt = 0; kt < 2; ++kt) {
                bf16x8 A;
                #pragma unroll
                for (int j = 0; j < 8; ++j)
                    A[j] = (short)f2bf(nsr[kt * 8 + j] * sv);
                #pragma unroll
                for (int nt = 0; nt < 8; ++nt) {
                    bf16x8 B = *(const bf16x8*)(bsf +
                        (size_t)((32 + v * 16 + kt * 8 + nt) * 64 + lane) * 8);
                    Ds[nt] = __builtin_amdgcn_mfma_f32_16x16x32_bf16(A, B, Ds[nt], 0, 0, 0);
                }
            }
        }
    }
    #pragma unroll
    for (int nt = 0; nt < 4; ++nt)
        #pragma unroll
        for (int r = 0; r < 4; ++r) {
            out[(size_t)(n0 + q * 4 + r) * 256 + nt * 16 + c] = silu_n(Ds[nt][r]);
            gbuf[(size_t)(n0 + q * 4 + r) * 64 + nt * 16 + c] = silu_n(Ds[4 + nt][r]);
        }
}

// ---------------------------------------------------------------------------
// Kernel C2: vector epilogue — one wave per (16-node tile, p). (unchanged)
// ---------------------------------------------------------------------------
__global__ __launch_bounds__(256) void k_node_out_v(
    const float* __restrict__ nv, const float* __restrict__ na,
    const unsigned short* __restrict__ bvf,
    const float* __restrict__ v_agg, const float* __restrict__ gbuf,
    float* __restrict__ out)
{
    const size_t NP2 = (size_t)N_NODES * 128;
    int lane = threadIdx.x & 63;
    int gwave = (blockIdx.x * blockDim.x + threadIdx.x) >> 6;
    if (gwave >= 3750) return;
    int p = __builtin_amdgcn_readfirstlane(gwave % 3);
    int n0 = __builtin_amdgcn_readfirstlane((gwave / 3) * 16);
    int q = lane >> 4, c = lane & 15;
    int node = n0 + c;

    float pa[4];
    #pragma unroll
    for (int v = 0; v < 4; ++v) pa[v] = na[(size_t)node * 4 + v];

    f32x4 Dv[4];
    #pragma unroll
    for (int nt = 0; nt < 4; ++nt) Dv[nt] = (f32x4){0.f, 0.f, 0.f, 0.f};

    #pragma unroll
    for (int kt = 0; kt < 4; ++kt) {
        const float* ap = v_agg + (size_t)p * NP2 + (size_t)node * 128 + kt * 32 + q * 8;
        float4 a0 = *(const float4*)ap;
        float4 a1 = *(const float4*)(ap + 4);
        bf16x8 A;
        A[0] = (short)f2bf(a0.x); A[1] = (short)f2bf(a0.y);
        A[2] = (short)f2bf(a0.z); A[3] = (short)f2bf(a0.w);
        A[4] = (short)f2bf(a1.x); A[5] = (short)f2bf(a1.y);
        A[6] = (short)f2bf(a1.z); A[7] = (short)f2bf(a1.w);
        #pragma unroll
        for (int nt = 0; nt < 4; ++nt) {
            bf16x8 B = *(const bf16x8*)(bvf + (size_t)((kt * 4 + nt) * 64 + lane) * 8);
            Dv[nt] = __builtin_amdgcn_mfma_f32_16x16x32_bf16(A, B, Dv[nt], 0, 0, 0);
        }
    }
    float nvr[16];
    #pragma unroll
    for (int j = 0; j < 8; ++j) {
        nvr[j]     = nv[(size_t)node * 192 + (size_t)(q * 8 + j) * 3 + p];
        nvr[8 + j] = nv[(size_t)node * 192 + (size_t)(32 + q * 8 + j) * 3 + p];
    }
    #pragma unroll
    for (int v = 0; v < 4; ++v) {
        float sv = pa[v];
        #pragma unroll
        for (int kt = 0; kt < 2; ++kt) {
            bf16x8 A;
            #pragma unroll
            for (int j = 0; j < 8; ++j)
                A[j] = (short)f2bf(nvr[kt * 8 + j] * sv);
            #pragma unroll
            for (int nt = 0; nt < 4; ++nt) {
                bf16x8 B = *(const bf16x8*)(bvf +
                    (size_t)((16 + v * 8 + kt * 4 + nt) * 64 + lane) * 8);
                Dv[nt] = __builtin_amdgcn_mfma_f32_16x16x32_bf16(A, B, Dv[nt], 0, 0, 0);
            }
        }
    }
    #pragma unroll
    for (int nt = 0; nt < 4; ++nt)
        #pragma unroll
        for (int r = 0; r < 4; ++r) {
            int w = nt * 16 + c;
            float g = gbuf[(size_t)(n0 + q * 4 + r) * 64 + w];
            out[(size_t)(n0 + q * 4 + r) * 256 + 64 + (size_t)w * 3 + p] = g * Dv[nt][r];
        }
}

// ---------------------------------------------------------------------------
extern "C" void kernel_launch(void* const* d_in, const int* in_sizes, int n_in,
                              void* d_out, int out_size, void* d_ws, size_t ws_size,
                              hipStream_t stream)
{
    const float* node_scalars = (const float*)d_in[0];
    const float* node_vectors = (const float*)d_in[1];
    const float* node_attr    = (const float*)d_in[2];
    const float* edge_sh      = (const float*)d_in[3];
    const float* edge_emb     = (const float*)d_in[4];
    const int*   edge_src     = (const int*)d_in[5];
    const int*   edge_dst     = (const int*)d_in[6];
    const float* W_lin1_s = (const float*)d_in[7];
    const float* W_lin1_v = (const float*)d_in[8];
    const float* W_fc0    = (const float*)d_in[9];
    const float* W_fc1    = (const float*)d_in[10];
    const float* W_fc2    = (const float*)d_in[11];
    const float* W_lin2_s = (const float*)d_in[12];
    const float* W_lin2_v = (const float*)d_in[13];
    const float* W_sc_s   = (const float*)d_in[14];
    const float* W_sc_v   = (const float*)d_in[15];
    float* out = (float*)d_out;

    // workspace layout (all sub-arrays stay 16B-aligned)
    float* ws    = (float*)d_ws;
    float* s_agg = ws;                                    // N*128
    float* v_agg = s_agg + (size_t)N_NODES * 128;         // 3*N*128
    float* s_buf = v_agg + 3 * (size_t)N_NODES * 128;     // N*64
    float* v_buf = s_buf + (size_t)N_NODES * 64;          // 3*N*64
    float* gbuf  = v_buf + 3 * (size_t)N_NODES * 64;      // N*64
    int*   counts = (int*)(gbuf + (size_t)N_NODES * 64);  // N
    int*   cursor = counts + N_NODES;                     // N
    int*   dlist  = cursor + N_NODES;                     // E
    int*   slist  = dlist + N_EDGES;                      // E
    unsigned short* w1f  = (unsigned short*)(slist + N_EDGES);  // 4096
    unsigned short* w2f  = w1f + 4096;                    // 16384
    unsigned short* bsf  = w2f + 16384;                   // 49152
    unsigned short* bvf  = bsf + 49152;                   // 24576
    unsigned short* w0f  = bvf + 24576;                   // 2048
    unsigned short* l1sf = w0f + 2048;                    // 4096
    unsigned short* l1vf = l1sf + 4096;                   // 4096
    float4* ysort = (float4*)(l1vf + 4096);               // E float4
    float4* esort = ysort + N_EDGES;                      // E x 2 float4

    // D1: wprep + zero(s_agg..v_agg, counts)
    {
        k_pre<<<WPREP_BLOCKS + 2048, 256, 0, stream>>>(
            W_fc1, W_fc2, W_lin2_s, W_lin2_v, W_sc_s, W_sc_v,
            W_fc0, W_lin1_s, W_lin1_v,
            w1f, w2f, bsf, bvf, w0f, l1sf, l1vf,
            (float4*)s_agg, counts);
    }
    // D2: histogram
    {
        int blocks = (N_EDGES + 255) / 256;
        k_hist<<<blocks, 256, 0, stream>>>(edge_dst, counts);
    }
    // D3: scan
    k_scan<<<1, SCAN_T, 0, stream>>>(counts, cursor);
    // D4: fill + lin1 (independent halves, single launch)
    {
        k_fill_lin1<<<FILL_BLOCKS + 1250, 256, 0, stream>>>(
            edge_dst, edge_src, edge_sh, edge_emb, cursor,
            dlist, slist, ysort, esort,
            node_scalars, node_vectors, l1sf, l1vf, s_buf, v_buf);
    }
    // D5: fused edge pipeline (16-edge gather staging)
    {
        int blocks = N_EDGES / 256;    // 1250
        k_edge_fused<<<blocks, 256, 0, stream>>>((const float*)esort, w0f, w1f, w2f,
                                                 slist, dlist, (const float*)ysort,
                                                 s_buf, v_buf, s_agg, v_agg);
    }
    // D6: scalar epilogue (out_s + gate)
    {
        int blocks = (1250 + 3) / 4;
        k_node_out_s<<<blocks, 256, 0, stream>>>(node_scalars, node_attr, bsf,
                                                 s_agg, out, gbuf);
    }
    // D7: vector epilogue
    {
        int blocks = (3750 + 3) / 4;
        k_node_out_v<<<blocks, 256, 0, stream>>>(node_vectors, node_attr, bvf,
                                                 v_agg, gbuf, out);
    }
}

// Round 13
// 318.377 us; speedup vs baseline: 1.0934x; 1.0934x over previous
//
#include <hip/hip_runtime.h>
#include <math.h>

#define N_NODES 20000
#define N_EDGES 320000
#define MUL 64
#define NUM_BASIS 8
#define HID 64
#define NSPEC 4

#define LIN_NORM     0.125f          // 1/sqrt(64)
#define INV_SQRT8    0.3535533906f   // 1/sqrt(8)
#define LIN2_NORM    0.08838834765f  // 1/sqrt(128)
#define SC_NORM      0.0625f         // 1/sqrt(64*4)
#define INV_NEIGH    0.0625f         // 1/16
#define INV_SQRT3    0.5773502692f
#define SILU_NORM    1.679177f

typedef __attribute__((ext_vector_type(8))) short bf16x8;
typedef __attribute__((ext_vector_type(4))) float f32x4;

__device__ __forceinline__ float silu_n(float x) {
    float s = 1.0f / (1.0f + __expf(-x));
    return x * s * SILU_NORM;
}

__device__ __forceinline__ float bcast(float x, int l) {
    return __uint_as_float(__builtin_amdgcn_readlane(__float_as_uint(x), l));
}
__device__ __forceinline__ int bcast_i(int x, int l) {
    return __builtin_amdgcn_readlane(x, l);
}

// fp32 -> bf16 with round-to-nearest-even
__device__ __forceinline__ unsigned short f2bf(float x) {
    unsigned int u = __float_as_uint(x);
    unsigned int r = (u + 0x7fffu + ((u >> 16) & 1u)) >> 16;
    return (unsigned short)r;
}

// packed 2x bf16 convert: D[15:0]=bf16(lo), D[31:16]=bf16(hi)
__device__ __forceinline__ unsigned int cvtpk(float lo, float hi) {
    unsigned int r;
    asm("v_cvt_pk_bf16_f32 %0, %1, %2" : "=v"(r) : "v"(lo), "v"(hi));
    return r;
}

__device__ __forceinline__ bf16x8 cvt8(float f0, float f1, float f2, float f3,
                                       float f4, float f5, float f6, float f7) {
    union { unsigned int u[4]; bf16x8 v; } r;
    r.u[0] = cvtpk(f0, f1);
    r.u[1] = cvtpk(f2, f3);
    r.u[2] = cvtpk(f4, f5);
    r.u[3] = cvtpk(f6, f7);
    return r.v;
}

// ---------------------------------------------------------------------------
// k_pre: blocks 0-50 = weight swizzle (13056 threads); blocks 51+ = grid-stride
// zero of s_agg..v_agg (N*512 floats, float4) + counts.
// ---------------------------------------------------------------------------
#define WPREP_BLOCKS 51
__global__ __launch_bounds__(256) void k_pre(
    const float* __restrict__ W1, const float* __restrict__ W2,
    const float* __restrict__ Wl2s, const float* __restrict__ Wl2v,
    const float* __restrict__ Wscs, const float* __restrict__ Wscv,
    const float* __restrict__ W0,
    const float* __restrict__ Wl1s, const float* __restrict__ Wl1v,
    unsigned short* __restrict__ w1f, unsigned short* __restrict__ w2f,
    unsigned short* __restrict__ bsf, unsigned short* __restrict__ bvf,
    unsigned short* __restrict__ w0f,
    unsigned short* __restrict__ l1sf, unsigned short* __restrict__ l1vf,
    float4* __restrict__ agg4, int* __restrict__ counts)
{
    if (blockIdx.x >= WPREP_BLOCKS) {
        int idx = (blockIdx.x - WPREP_BLOCKS) * 256 + threadIdx.x;
        int nthr = (gridDim.x - WPREP_BLOCKS) * 256;
        const size_t total4 = (size_t)N_NODES * 128;   // N*512 floats
        float4 z = {0.f, 0.f, 0.f, 0.f};
        for (size_t i = idx; i < total4; i += nthr) agg4[i] = z;
        if (idx < N_NODES) counts[idx] = 0;
        return;
    }
    int t = blockIdx.x * 256 + threadIdx.x;
    if (t < 512) {                       // W1: 8 frags (kt*4+nt)
        int f = t >> 6, lane = t & 63;
        int kt = f >> 2, nt = f & 3, q = lane >> 4, c = lane & 15;
        #pragma unroll
        for (int j = 0; j < 8; ++j) {
            int k = kt * 32 + q * 8 + j;
            int n = nt * 16 + c;
            w1f[(size_t)t * 8 + j] = f2bf(W1[k * 64 + n]);
        }
    } else if (t < 2560) {               // W2: 32 frags (kt*16+nt)
        int tt = t - 512;
        int f = tt >> 6, lane = tt & 63;
        int kt = f >> 4, nt = f & 15, q = lane >> 4, c = lane & 15;
        #pragma unroll
        for (int j = 0; j < 8; ++j) {
            int k = kt * 32 + q * 8 + j;
            int n = nt * 16 + c;
            w2f[(size_t)tt * 8 + j] = f2bf(W2[k * 256 + n]);
        }
    } else if (t < 4608) {               // bs_lin: 32 frags, 128x128
        int tt = t - 2560;
        int f = tt >> 6, lane = tt & 63;
        int kt = f >> 3, nt = f & 7, q = lane >> 4, c = lane & 15;
        #pragma unroll
        for (int j = 0; j < 8; ++j) {
            int k = kt * 32 + q * 8 + j;
            int n = nt * 16 + c;
            bsf[(size_t)tt * 8 + j] = f2bf(Wl2s[k * 128 + n] * LIN2_NORM);
        }
    } else if (t < 8704) {               // bs_sc: 64 frags (v*16+kt*8+nt), 64x128 per v
        int tt = t - 4608;
        int f = tt >> 6, lane = tt & 63;
        int v = f >> 4, g = f & 15;
        int kt = g >> 3, nt = g & 7, q = lane >> 4, c = lane & 15;
        #pragma unroll
        for (int j = 0; j < 8; ++j) {
            int u = kt * 32 + q * 8 + j;          // u < 64
            int n = nt * 16 + c;
            bsf[(size_t)(2048 + tt) * 8 + j] = f2bf(Wscs[(u * 4 + v) * 128 + n] * SC_NORM);
        }
    } else if (t < 9728) {               // bv_lin: 16 frags, 128x64
        int tt = t - 8704;
        int f = tt >> 6, lane = tt & 63;
        int kt = f >> 2, nt = f & 3, q = lane >> 4, c = lane & 15;
        #pragma unroll
        for (int j = 0; j < 8; ++j) {
            int k = kt * 32 + q * 8 + j;
            int n = nt * 16 + c;
            bvf[(size_t)tt * 8 + j] = f2bf(Wl2v[k * 64 + n] * LIN2_NORM);
        }
    } else if (t < 11776) {              // bv_sc: 32 frags (v*8+kt*4+nt), 64x64 per v
        int tt = t - 9728;
        int f = tt >> 6, lane = tt & 63;
        int v = f >> 3, g = f & 7;
        int kt = g >> 2, nt = g & 3, q = lane >> 4, c = lane & 15;
        #pragma unroll
        for (int j = 0; j < 8; ++j) {
            int u = kt * 32 + q * 8 + j;          // u < 64
            int n = nt * 16 + c;
            bvf[(size_t)(1024 + tt) * 8 + j] = f2bf(Wscv[(u * 4 + v) * 64 + n] * SC_NORM);
        }
    } else if (t < 12032) {              // w0f: 4 frags (nt), K=8 padded to 32
        int tt = t - 11776;
        int f = tt >> 6, lane = tt & 63;
        int q = lane >> 4, c = lane & 15;
        #pragma unroll
        for (int j = 0; j < 8; ++j) {
            int k = q * 8 + j;
            int n = f * 16 + c;
            w0f[(size_t)tt * 8 + j] =
                (k < 8) ? f2bf(W0[k * 64 + n] * INV_SQRT8) : (unsigned short)0;
        }
    } else if (t < 12544) {              // l1sf: 8 frags (kt*4+nt), LIN_NORM folded
        int tt = t - 12032;
        int f = tt >> 6, lane = tt & 63;
        int kt = f >> 2, nt = f & 3, q = lane >> 4, c = lane & 15;
        #pragma unroll
        for (int j = 0; j < 8; ++j) {
            int k = kt * 32 + q * 8 + j;
            int n = nt * 16 + c;
            l1sf[(size_t)tt * 8 + j] = f2bf(Wl1s[k * 64 + n] * LIN_NORM);
        }
    } else if (t < 13056) {              // l1vf: 8 frags (kt*4+nt), LIN_NORM folded
        int tt = t - 12544;
        int f = tt >> 6, lane = tt & 63;
        int kt = f >> 2, nt = f & 3, q = lane >> 4, c = lane & 15;
        #pragma unroll
        for (int j = 0; j < 8; ++j) {
            int k = kt * 32 + q * 8 + j;
            int n = nt * 16 + c;
            l1vf[(size_t)tt * 8 + j] = f2bf(Wl1v[k * 64 + n] * LIN_NORM);
        }
    }
}

// ---------------------------------------------------------------------------
// CSR build: histogram -> 1-block scan (unchanged bodies)
// ---------------------------------------------------------------------------
__global__ __launch_bounds__(256) void k_hist(const int* __restrict__ edst,
                                              int* __restrict__ counts)
{
    int e = blockIdx.x * blockDim.x + threadIdx.x;
    if (e < N_EDGES) atomicAdd(&counts[edst[e]], 1);
}

#define SCAN_T 1024
__global__ __launch_bounds__(SCAN_T) void k_scan(const int* __restrict__ counts,
                                                 int* __restrict__ cursor)
{
    __shared__ int part[SCAN_T];
    int t = threadIdx.x;
    const int CH = (N_NODES + SCAN_T - 1) / SCAN_T;   // 20
    int b0 = t * CH;
    int s = 0;
    for (int i = 0; i < CH; ++i) {
        int idx = b0 + i;
        if (idx < N_NODES) s += counts[idx];
    }
    part[t] = s;
    __syncthreads();
    for (int off = 1; off < SCAN_T; off <<= 1) {
        int v = (t >= off) ? part[t - off] : 0;
        __syncthreads();
        part[t] += v;
        __syncthreads();
    }
    int run = (t == 0) ? 0 : part[t - 1];
    for (int i = 0; i < CH; ++i) {
        int idx = b0 + i;
        if (idx < N_NODES) {
            cursor[idx] = run;
            run += counts[idx];
        }
    }
}

// ---------------------------------------------------------------------------
// k_fill_lin1: blocks 0-1249 = edge-payload scatter; blocks 1250+ = node lin1
// on MFMA (4-way wave split). Bodies unchanged.
// ---------------------------------------------------------------------------
#define FILL_BLOCKS 1250
__global__ __launch_bounds__(256) void k_fill_lin1(
    const int* __restrict__ edst, const int* __restrict__ esrc,
    const float* __restrict__ sh, const float* __restrict__ emb,
    int* __restrict__ cursor,
    int* __restrict__ dlist, int* __restrict__ slist,
    float4* __restrict__ ysort, float4* __restrict__ esort,
    const float* __restrict__ ns, const float* __restrict__ nv,
    const unsigned short* __restrict__ l1sf, const unsigned short* __restrict__ l1vf,
    float* __restrict__ s_out, float* __restrict__ v_out)
{
    if (blockIdx.x < FILL_BLOCKS) {
        int e = blockIdx.x * blockDim.x + threadIdx.x;
        if (e < N_EDGES) {
            int d = edst[e];
            int pos = atomicAdd(&cursor[d], 1);
            dlist[pos] = d;
            slist[pos] = esrc[e];
            ysort[pos] = ((const float4*)sh)[e];
            esort[(size_t)pos * 2]     = ((const float4*)emb)[(size_t)e * 2];
            esort[(size_t)pos * 2 + 1] = ((const float4*)emb)[(size_t)e * 2 + 1];
        }
        return;
    }
    const size_t NV = (size_t)N_NODES * 64;
    int lane = threadIdx.x & 63;
    int gwave = ((blockIdx.x - FILL_BLOCKS) * 256 + threadIdx.x) >> 6;
    int part = __builtin_amdgcn_readfirstlane(gwave & 3);
    int n0 = __builtin_amdgcn_readfirstlane((gwave >> 2) * 16);
    if (n0 >= N_NODES) return;
    int q = lane >> 4, c = lane & 15;
    int node = n0 + c;

    if (part == 0) {
        f32x4 Ds[4];
        #pragma unroll
        for (int nt = 0; nt < 4; ++nt) Ds[nt] = (f32x4){0.f, 0.f, 0.f, 0.f};
        #pragma unroll
        for (int kt = 0; kt < 2; ++kt) {
            const float* ap = ns + (size_t)node * 64 + kt * 32 + q * 8;
            float4 a0 = *(const float4*)ap;
            float4 a1 = *(const float4*)(ap + 4);
            bf16x8 A = cvt8(a0.x, a0.y, a0.z, a0.w, a1.x, a1.y, a1.z, a1.w);
            #pragma unroll
            for (int nt = 0; nt < 4; ++nt) {
                bf16x8 B = *(const bf16x8*)(l1sf + (size_t)((kt * 4 + nt) * 64 + lane) * 8);
                Ds[nt] = __builtin_amdgcn_mfma_f32_16x16x32_bf16(A, B, Ds[nt], 0, 0, 0);
            }
        }
        #pragma unroll
        for (int nt = 0; nt < 4; ++nt)
            #pragma unroll
            for (int r = 0; r < 4; ++r)
                s_out[(size_t)(n0 + q * 4 + r) * 64 + nt * 16 + c] = Ds[nt][r];
    } else {
        int p = part - 1;
        f32x4 Dv[4];
        #pragma unroll
        for (int nt = 0; nt < 4; ++nt) Dv[nt] = (f32x4){0.f, 0.f, 0.f, 0.f};
        #pragma unroll
        for (int kt = 0; kt < 2; ++kt) {
            float f[8];
            #pragma unroll
            for (int j = 0; j < 8; ++j)
                f[j] = nv[(size_t)node * 192 + (size_t)(kt * 32 + q * 8 + j) * 3 + p];
            bf16x8 A = cvt8(f[0], f[1], f[2], f[3], f[4], f[5], f[6], f[7]);
            #pragma unroll
            for (int nt = 0; nt < 4; ++nt) {
                bf16x8 B = *(const bf16x8*)(l1vf + (size_t)((kt * 4 + nt) * 64 + lane) * 8);
                Dv[nt] = __builtin_amdgcn_mfma_f32_16x16x32_bf16(A, B, Dv[nt], 0, 0, 0);
            }
        }
        #pragma unroll
        for (int nt = 0; nt < 4; ++nt)
            #pragma unroll
            for (int r = 0; r < 4; ++r)
                v_out[p * NV + (size_t)(n0 + q * 4 + r) * 64 + nt * 16 + c] = Dv[nt][r];
    }
}

// ---------------------------------------------------------------------------
// Kernel B (FUSED): edge MLP + TP + run-merge scatter. R10-proven compute body
// (8-edge staged scatter), with LDS ALIASED: wl1 overlays the h0+h1 region
// (dead after A1 ds_read; same-wave DS ops are in-order). Per-wave 8832 B ->
// block 35,328 B -> 4 blocks/CU (was 3).
// ---------------------------------------------------------------------------
__global__ __launch_bounds__(256) void k_edge_fused(
    const float* __restrict__ esort,
    const unsigned short* __restrict__ w0f,
    const unsigned short* __restrict__ w1f, const unsigned short* __restrict__ w2f,
    const int* __restrict__ slist, const int* __restrict__ dlist,
    const float* __restrict__ ysort,
    const float* __restrict__ s_in, const float* __restrict__ v_in,
    float* __restrict__ s_agg, float* __restrict__ v_agg)
{
    const size_t NP2 = (size_t)N_NODES * 128;
    const size_t NV  = (size_t)N_NODES * 64;

    // per-wave pool: [0,2304)=h0 | [2304,4608)=h1 | wl1 aliases [0,4224) |
    // [4608,8832)=wl2.  All sub-bases 16B-aligned (8832 = 552*16).
    __shared__ __align__(16) unsigned char pool[4 * 8832];

    int lane = threadIdx.x & 63;
    int wid  = threadIdx.x >> 6;
    int q = lane >> 4;
    int c = lane & 15;
    int lbase = __builtin_amdgcn_readfirstlane(blockIdx.x * 256 + wid * 64);
    unsigned char* base = pool + wid * 8832;
    unsigned short* myh0 = (unsigned short*)base;            // 16*72 bf16
    unsigned short* myh1 = (unsigned short*)(base + 2304);   // 16*72 bf16
    unsigned int*   myw1 = (unsigned int*)base;              // 16*66 uint (aliases h)
    unsigned int*   myw2 = (unsigned int*)(base + 4608);     // 16*66 uint

    int srcv = slist[lbase + lane];
    int dstv = dlist[lbase + lane];
    float4 y4 = ((const float4*)ysort)[lbase + lane];

    bf16x8 B0[4];
    #pragma unroll
    for (int f = 0; f < 4; ++f)
        B0[f] = *(const bf16x8*)(w0f + (size_t)(f * 64 + lane) * 8);
    bf16x8 B1[2][4];
    #pragma unroll
    for (int f = 0; f < 8; ++f)
        B1[f >> 2][f & 3] = *(const bf16x8*)(w1f + (size_t)(f * 64 + lane) * 8);

    const float4* e4 = (const float4*)esort;
    const float WS  = 0.125f * INV_NEIGH;
    const float WSD = WS * INV_SQRT3;

    float accA = 0.f, aB0 = 0.f, aB1 = 0.f, aB2 = 0.f;
    float accD = 0.f, aC0 = 0.f, aC1 = 0.f, aC2 = 0.f;
    int cur = bcast_i(dstv, 0);

    #pragma unroll 1
    for (int mt = 0; mt < 4; ++mt) {
        int tb16 = mt * 16;

        // ======== MLP phase (all MFMA, lgkm-only waits) ========
        float4 ea = {0.f, 0.f, 0.f, 0.f}, eb = {0.f, 0.f, 0.f, 0.f};
        if (q == 0) {
            ea = e4[(size_t)(lbase + tb16 + c) * 2];
            eb = e4[(size_t)(lbase + tb16 + c) * 2 + 1];
        }
        bf16x8 Ae = cvt8(ea.x, ea.y, ea.z, ea.w, eb.x, eb.y, eb.z, eb.w);
        f32x4 D0[4];
        #pragma unroll
        for (int nt = 0; nt < 4; ++nt) {
            f32x4 z = {0.f, 0.f, 0.f, 0.f};
            D0[nt] = __builtin_amdgcn_mfma_f32_16x16x32_bf16(Ae, B0[nt], z, 0, 0, 0);
        }
        #pragma unroll
        for (int nt = 0; nt < 4; ++nt)
            #pragma unroll
            for (int r = 0; r < 4; ++r)
                myh0[(q * 4 + r) * 72 + nt * 16 + c] = f2bf(silu_n(D0[nt][r]));
        __builtin_amdgcn_s_waitcnt(0xC07F);   // lgkmcnt(0) ONLY
        bf16x8 A0[2];
        #pragma unroll
        for (int kt = 0; kt < 2; ++kt)
            A0[kt] = *(const bf16x8*)(myh0 + c * 72 + kt * 32 + q * 8);

        f32x4 D1[4];
        #pragma unroll
        for (int nt = 0; nt < 4; ++nt) {
            f32x4 z = {0.f, 0.f, 0.f, 0.f};
            D1[nt] = __builtin_amdgcn_mfma_f32_16x16x32_bf16(A0[0], B1[0][nt], z, 0, 0, 0);
            D1[nt] = __builtin_amdgcn_mfma_f32_16x16x32_bf16(A0[1], B1[1][nt], D1[nt], 0, 0, 0);
        }
        #pragma unroll
        for (int nt = 0; nt < 4; ++nt)
            #pragma unroll
            for (int r = 0; r < 4; ++r)
                myh1[(q * 4 + r) * 72 + nt * 16 + c] = f2bf(silu_n(D1[nt][r] * 0.125f));
        __builtin_amdgcn_s_waitcnt(0xC07F);   // lgkmcnt(0) ONLY
        bf16x8 A1[2];
        #pragma unroll
        for (int kt = 0; kt < 2; ++kt)
            A1[kt] = *(const bf16x8*)(myh1 + c * 72 + kt * 32 + q * 8);
        // A1 now in registers: h region dead, wl1 may overwrite it.

        #pragma unroll
        for (int half = 0; half < 2; ++half) {
            int ga = half * 2, gb = half * 2 + 1;
            f32x4 Da[4], Db[4];
            #pragma unroll
            for (int ntl = 0; ntl < 4; ++ntl) {
                bf16x8 b0 = *(const bf16x8*)(w2f + (size_t)((ga * 4 + ntl) * 64 + lane) * 8);
                bf16x8 b1 = *(const bf16x8*)(w2f + (size_t)((16 + ga * 4 + ntl) * 64 + lane) * 8);
                f32x4 z = {0.f, 0.f, 0.f, 0.f};
                Da[ntl] = __builtin_amdgcn_mfma_f32_16x16x32_bf16(A1[0], b0, z, 0, 0, 0);
                Da[ntl] = __builtin_amdgcn_mfma_f32_16x16x32_bf16(A1[1], b1, Da[ntl], 0, 0, 0);
            }
            #pragma unroll
            for (int ntl = 0; ntl < 4; ++ntl) {
                bf16x8 b0 = *(const bf16x8*)(w2f + (size_t)((gb * 4 + ntl) * 64 + lane) * 8);
                bf16x8 b1 = *(const bf16x8*)(w2f + (size_t)((16 + gb * 4 + ntl) * 64 + lane) * 8);
                f32x4 z = {0.f, 0.f, 0.f, 0.f};
                Db[ntl] = __builtin_amdgcn_mfma_f32_16x16x32_bf16(A1[0], b0, z, 0, 0, 0);
                Db[ntl] = __builtin_amdgcn_mfma_f32_16x16x32_bf16(A1[1], b1, Db[ntl], 0, 0, 0);
            }
            float sb = half ? WSD : WS;
            unsigned int* pp = half ? myw2 : myw1;
            #pragma unroll
            for (int ntl = 0; ntl < 4; ++ntl)
                #pragma unroll
                for (int r = 0; r < 4; ++r)
                    pp[(q * 4 + r) * 66 + ntl * 16 + c] = cvtpk(Da[ntl][r] * WS, Db[ntl][r] * sb);
        }
        __builtin_amdgcn_s_waitcnt(0xC07F);   // drain LDS writes before reads

        // ======== scatter phase: 16 edges, staged 8 at a time (R10-proven) ========
        #pragma unroll 1
        for (int ebl = 0; ebl < 16; ebl += 8) {
            float se8[8], v08[8], v18[8], v28[8];
            unsigned int wab[8], wcd[8];
            #pragma unroll
            for (int i = 0; i < 8; ++i) {
                int et = ebl + i;                       // tile-local 0..15
                int src = bcast_i(srcv, tb16 + et);
                wab[i] = myw1[et * 66 + lane];
                wcd[i] = myw2[et * 66 + lane];
                se8[i] = s_in[(size_t)src * 64 + lane];
                v08[i] = v_in[0 * NV + (size_t)src * 64 + lane];
                v18[i] = v_in[1 * NV + (size_t)src * 64 + lane];
                v28[i] = v_in[2 * NV + (size_t)src * 64 + lane];
            }
            #pragma unroll
            for (int i = 0; i < 8; ++i) {
                int e = tb16 + ebl + i;
                int dst = bcast_i(dstv, e);
                float y0 = bcast(y4.x, e), yx = bcast(y4.y, e);
                float yy = bcast(y4.z, e), yz = bcast(y4.w, e);
                if (dst != cur) {
                    size_t db = (size_t)cur * 128;
                    unsafeAtomicAdd(&s_agg[db + lane], accA);
                    unsafeAtomicAdd(&s_agg[db + 64 + lane], accD);
                    unsafeAtomicAdd(&v_agg[0 * NP2 + db + lane], aB0);
                    unsafeAtomicAdd(&v_agg[1 * NP2 + db + lane], aB1);
                    unsafeAtomicAdd(&v_agg[2 * NP2 + db + lane], aB2);
                    unsafeAtomicAdd(&v_agg[0 * NP2 + db + 64 + lane], aC0);
                    unsafeAtomicAdd(&v_agg[1 * NP2 + db + 64 + lane], aC1);
                    unsafeAtomicAdd(&v_agg[2 * NP2 + db + 64 + lane], aC2);
                    accA = aB0 = aB1 = aB2 = 0.f;
                    accD = aC0 = aC1 = aC2 = 0.f;
                    cur = dst;
                }
                float wA = __uint_as_float(wab[i] << 16);
                float wB = __uint_as_float(wab[i] & 0xffff0000u);
                float wC = __uint_as_float(wcd[i] << 16);
                float wD = __uint_as_float(wcd[i] & 0xffff0000u);  // INV_SQRT3 folded
                accA = fmaf(wA, se8[i] * y0, accA);
                float bB = wB * se8[i];
                aB0 = fmaf(bB, yx, aB0);
                aB1 = fmaf(bB, yy, aB1);
                aB2 = fmaf(bB, yz, aB2);
                float dot = v08[i] * yx + v18[i] * yy + v28[i] * yz;
                accD = fmaf(wD, dot, accD);
                float bC = wC * y0;
                aC0 = fmaf(bC, v08[i], aC0);
                aC1 = fmaf(bC, v18[i], aC1);
                aC2 = fmaf(bC, v28[i], aC2);
            }
        }
    }
    // final flush
    {
        size_t db = (size_t)cur * 128;
        unsafeAtomicAdd(&s_agg[db + lane], accA);
        unsafeAtomicAdd(&s_agg[db + 64 + lane], accD);
        unsafeAtomicAdd(&v_agg[0 * NP2 + db + lane], aB0);
        unsafeAtomicAdd(&v_agg[1 * NP2 + db + lane], aB1);
        unsafeAtomicAdd(&v_agg[2 * NP2 + db + lane], aB2);
        unsafeAtomicAdd(&v_agg[0 * NP2 + db + 64 + lane], aC0);
        unsafeAtomicAdd(&v_agg[1 * NP2 + db + 64 + lane], aC1);
        unsafeAtomicAdd(&v_agg[2 * NP2 + db + 64 + lane], aC2);
    }
}

// ---------------------------------------------------------------------------
// Kernel C1: scalar epilogue — out_s + gate -> global gbuf. (unchanged)
// ---------------------------------------------------------------------------
__global__ __launch_bounds__(256) void k_node_out_s(
    const float* __restrict__ ns, const float* __restrict__ na,
    const unsigned short* __restrict__ bsf,
    const float* __restrict__ s_agg,
    float* __restrict__ out, float* __restrict__ gbuf)
{
    int lane = threadIdx.x & 63;
    int wtile = (blockIdx.x * blockDim.x + threadIdx.x) >> 6;
    int n0 = __builtin_amdgcn_readfirstlane(wtile * 16);
    if (n0 >= N_NODES) return;
    int q = lane >> 4, c = lane & 15;
    int node = n0 + c;

    float pa[4];
    #pragma unroll
    for (int v = 0; v < 4; ++v) pa[v] = na[(size_t)node * 4 + v];

    f32x4 Ds[8];
    #pragma unroll
    for (int nt = 0; nt < 8; ++nt) Ds[nt] = (f32x4){0.f, 0.f, 0.f, 0.f};

    #pragma unroll
    for (int kt = 0; kt < 4; ++kt) {
        const float* ap = s_agg + (size_t)node * 128 + kt * 32 + q * 8;
        float4 a0 = *(const float4*)ap;
        float4 a1 = *(const float4*)(ap + 4);
        bf16x8 A;
        A[0] = (short)f2bf(a0.x); A[1] = (short)f2bf(a0.y);
        A[2] = (short)f2bf(a0.z); A[3] = (short)f2bf(a0.w);
        A[4] = (short)f2bf(a1.x); A[5] = (short)f2bf(a1.y);
        A[6] = (short)f2bf(a1.z); A[7] = (short)f2bf(a1.w);
        #pragma unroll
        for (int nt = 0; nt < 8; ++nt) {
            bf16x8 B = *(const bf16x8*)(bsf + (size_t)((kt * 8 + nt) * 64 + lane) * 8);
            Ds[nt] = __builtin_amdgcn_mfma_f32_16x16x32_bf16(A, B, Ds[nt], 0, 0, 0);
        }
    }
    {
        const float* np_ = ns + (size_t)node * 64 + q * 8;
        float4 n00 = *(const float4*)np_;
        float4 n01 = *(const float4*)(np_ + 4);
        float4 n10 = *(const float4*)(np_ + 32);
        float4 n11 = *(const float4*)(np_ + 36);
        float nsr[16] = {n00.x, n00.y, n00.z, n00.w, n01.x, n01.y, n01.z, n01.w,
                         n10.x, n10.y, n10.z, n10.w, n11.x, n11.y, n11.z, n11.w};
        #pragma unroll
        for (int v = 0; v < 4; ++v) {
            float sv = pa[v];
            #pragma unroll
            for (int kt = 0; kt < 2; ++kt) {
                bf16x8 A;
                #pragma unroll
                for (int j = 0; j < 8; ++j)
                    A[j] = (short)f2bf(nsr[kt * 8 + j] * sv);
                #pragma unroll
                for (int nt = 0; nt < 8; ++nt) {
                    bf16x8 B = *(const bf16x8*)(bsf +
                        (size_t)((32 + v * 16 + kt * 8 + nt) * 64 + lane) * 8);
                    Ds[nt] = __builtin_amdgcn_mfma_f32_16x16x32_bf16(A, B, Ds[nt], 0, 0, 0);
                }
            }
        }
    }
    #pragma unroll
    for (int nt = 0; nt < 4; ++nt)
        #pragma unroll
        for (int r = 0; r < 4; ++r) {
            out[(size_t)(n0 + q * 4 + r) * 256 + nt * 16 + c] = silu_n(Ds[nt][r]);
            gbuf[(size_t)(n0 + q * 4 + r) * 64 + nt * 16 + c] = silu_n(Ds[4 + nt][r]);
        }
}

// ---------------------------------------------------------------------------
// Kernel C2: vector epilogue — one wave per (16-node tile, p). (unchanged)
// ---------------------------------------------------------------------------
__global__ __launch_bounds__(256) void k_node_out_v(
    const float* __restrict__ nv, const float* __restrict__ na,
    const unsigned short* __restrict__ bvf,
    const float* __restrict__ v_agg, const float* __restrict__ gbuf,
    float* __restrict__ out)
{
    const size_t NP2 = (size_t)N_NODES * 128;
    int lane = threadIdx.x & 63;
    int gwave = (blockIdx.x * blockDim.x + threadIdx.x) >> 6;
    if (gwave >= 3750) return;
    int p = __builtin_amdgcn_readfirstlane(gwave % 3);
    int n0 = __builtin_amdgcn_readfirstlane((gwave / 3) * 16);
    int q = lane >> 4, c = lane & 15;
    int node = n0 + c;

    float pa[4];
    #pragma unroll
    for (int v = 0; v < 4; ++v) pa[v] = na[(size_t)node * 4 + v];

    f32x4 Dv[4];
    #pragma unroll
    for (int nt = 0; nt < 4; ++nt) Dv[nt] = (f32x4){0.f, 0.f, 0.f, 0.f};

    #pragma unroll
    for (int kt = 0; kt < 4; ++kt) {
        const float* ap = v_agg + (size_t)p * NP2 + (size_t)node * 128 + kt * 32 + q * 8;
        float4 a0 = *(const float4*)ap;
        float4 a1 = *(const float4*)(ap + 4);
        bf16x8 A;
        A[0] = (short)f2bf(a0.x); A[1] = (short)f2bf(a0.y);
        A[2] = (short)f2bf(a0.z); A[3] = (short)f2bf(a0.w);
        A[4] = (short)f2bf(a1.x); A[5] = (short)f2bf(a1.y);
        A[6] = (short)f2bf(a1.z); A[7] = (short)f2bf(a1.w);
        #pragma unroll
        for (int nt = 0; nt < 4; ++nt) {
            bf16x8 B = *(const bf16x8*)(bvf + (size_t)((kt * 4 + nt) * 64 + lane) * 8);
            Dv[nt] = __builtin_amdgcn_mfma_f32_16x16x32_bf16(A, B, Dv[nt], 0, 0, 0);
        }
    }
    float nvr[16];
    #pragma unroll
    for (int j = 0; j < 8; ++j) {
        nvr[j]     = nv[(size_t)node * 192 + (size_t)(q * 8 + j) * 3 + p];
        nvr[8 + j] = nv[(size_t)node * 192 + (size_t)(32 + q * 8 + j) * 3 + p];
    }
    #pragma unroll
    for (int v = 0; v < 4; ++v) {
        float sv = pa[v];
        #pragma unroll
        for (int kt = 0; kt < 2; ++kt) {
            bf16x8 A;
            #pragma unroll
            for (int j = 0; j < 8; ++j)
                A[j] = (short)f2bf(nvr[kt * 8 + j] * sv);
            #pragma unroll
            for (int nt = 0; nt < 4; ++nt) {
                bf16x8 B = *(const bf16x8*)(bvf +
                    (size_t)((16 + v * 8 + kt * 4 + nt) * 64 + lane) * 8);
                Dv[nt] = __builtin_amdgcn_mfma_f32_16x16x32_bf16(A, B, Dv[nt], 0, 0, 0);
            }
        }
    }
    #pragma unroll
    for (int nt = 0; nt < 4; ++nt)
        #pragma unroll
        for (int r = 0; r < 4; ++r) {
            int w = nt * 16 + c;
            float g = gbuf[(size_t)(n0 + q * 4 + r) * 64 + w];
            out[(size_t)(n0 + q * 4 + r) * 256 + 64 + (size_t)w * 3 + p] = g * Dv[nt][r];
        }
}

// ---------------------------------------------------------------------------
extern "C" void kernel_launch(void* const* d_in, const int* in_sizes, int n_in,
                              void* d_out, int out_size, void* d_ws, size_t ws_size,
                              hipStream_t stream)
{
    const float* node_scalars = (const float*)d_in[0];
    const float* node_vectors = (const float*)d_in[1];
    const float* node_attr    = (const float*)d_in[2];
    const float* edge_sh      = (const float*)d_in[3];
    const float* edge_emb     = (const float*)d_in[4];
    const int*   edge_src     = (const int*)d_in[5];
    const int*   edge_dst     = (const int*)d_in[6];
    const float* W_lin1_s = (const float*)d_in[7];
    const float* W_lin1_v = (const float*)d_in[8];
    const float* W_fc0    = (const float*)d_in[9];
    const float* W_fc1    = (const float*)d_in[10];
    const float* W_fc2    = (const float*)d_in[11];
    const float* W_lin2_s = (const float*)d_in[12];
    const float* W_lin2_v = (const float*)d_in[13];
    const float* W_sc_s   = (const float*)d_in[14];
    const float* W_sc_v   = (const float*)d_in[15];
    float* out = (float*)d_out;

    // workspace layout (all sub-arrays stay 16B-aligned)
    float* ws    = (float*)d_ws;
    float* s_agg = ws;                                    // N*128
    float* v_agg = s_agg + (size_t)N_NODES * 128;         // 3*N*128
    float* s_buf = v_agg + 3 * (size_t)N_NODES * 128;     // N*64
    float* v_buf = s_buf + (size_t)N_NODES * 64;          // 3*N*64
    float* gbuf  = v_buf + 3 * (size_t)N_NODES * 64;      // N*64
    int*   counts = (int*)(gbuf + (size_t)N_NODES * 64);  // N
    int*   cursor = counts + N_NODES;                     // N
    int*   dlist  = cursor + N_NODES;                     // E
    int*   slist  = dlist + N_EDGES;                      // E
    unsigned short* w1f  = (unsigned short*)(slist + N_EDGES);  // 4096
    unsigned short* w2f  = w1f + 4096;                    // 16384
    unsigned short* bsf  = w2f + 16384;                   // 49152
    unsigned short* bvf  = bsf + 49152;                   // 24576
    unsigned short* w0f  = bvf + 24576;                   // 2048
    unsigned short* l1sf = w0f + 2048;                    // 4096
    unsigned short* l1vf = l1sf + 4096;                   // 4096
    float4* ysort = (float4*)(l1vf + 4096);               // E float4
    float4* esort = ysort + N_EDGES;                      // E x 2 float4

    // D1: wprep + zero(s_agg..v_agg, counts)
    {
        k_pre<<<WPREP_BLOCKS + 2048, 256, 0, stream>>>(
            W_fc1, W_fc2, W_lin2_s, W_lin2_v, W_sc_s, W_sc_v,
            W_fc0, W_lin1_s, W_lin1_v,
            w1f, w2f, bsf, bvf, w0f, l1sf, l1vf,
            (float4*)s_agg, counts);
    }
    // D2: histogram
    {
        int blocks = (N_EDGES + 255) / 256;
        k_hist<<<blocks, 256, 0, stream>>>(edge_dst, counts);
    }
    // D3: scan
    k_scan<<<1, SCAN_T, 0, stream>>>(counts, cursor);
    // D4: fill + lin1 (independent halves, single launch)
    {
        k_fill_lin1<<<FILL_BLOCKS + 1250, 256, 0, stream>>>(
            edge_dst, edge_src, edge_sh, edge_emb, cursor,
            dlist, slist, ysort, esort,
            node_scalars, node_vectors, l1sf, l1vf, s_buf, v_buf);
    }
    // D5: fused edge pipeline (8-edge staging, aliased LDS -> 4 blocks/CU)
    {
        int blocks = N_EDGES / 256;    // 1250
        k_edge_fused<<<blocks, 256, 0, stream>>>((const float*)esort, w0f, w1f, w2f,
                                                 slist, dlist, (const float*)ysort,
                                                 s_buf, v_buf, s_agg, v_agg);
    }
    // D6: scalar epilogue (out_s + gate)
    {
        int blocks = (1250 + 3) / 4;
        k_node_out_s<<<blocks, 256, 0, stream>>>(node_scalars, node_attr, bsf,
                                                 s_agg, out, gbuf);
    }
    // D7: vector epilogue
    {
        int blocks = (3750 + 3) / 4;
        k_node_out_v<<<blocks, 256, 0, stream>>>(node_vectors, node_attr, bvf,
                                                 v_agg, gbuf, out);
    }
}

// Round 14
// 306.257 us; speedup vs baseline: 1.1367x; 1.0396x over previous
//
#include <hip/hip_runtime.h>
#include <math.h>

#define N_NODES 20000
#define N_EDGES 320000
#define MUL 64
#define NUM_BASIS 8
#define HID 64
#define NSPEC 4

#define LIN_NORM     0.125f          // 1/sqrt(64)
#define INV_SQRT8    0.3535533906f   // 1/sqrt(8)
#define LIN2_NORM    0.08838834765f  // 1/sqrt(128)
#define SC_NORM      0.0625f         // 1/sqrt(64*4)
#define INV_NEIGH    0.0625f         // 1/16
#define INV_SQRT3    0.5773502692f
#define SILU_NORM    1.679177f

typedef __attribute__((ext_vector_type(8))) short bf16x8;
typedef __attribute__((ext_vector_type(4))) float f32x4;

__device__ __forceinline__ float silu_n(float x) {
    float s = 1.0f / (1.0f + __expf(-x));
    return x * s * SILU_NORM;
}

__device__ __forceinline__ float bcast(float x, int l) {
    return __uint_as_float(__builtin_amdgcn_readlane(__float_as_uint(x), l));
}
__device__ __forceinline__ int bcast_i(int x, int l) {
    return __builtin_amdgcn_readlane(x, l);
}

// fp32 -> bf16 with round-to-nearest-even
__device__ __forceinline__ unsigned short f2bf(float x) {
    unsigned int u = __float_as_uint(x);
    unsigned int r = (u + 0x7fffu + ((u >> 16) & 1u)) >> 16;
    return (unsigned short)r;
}

// bf16 (as ushort) -> fp32
__device__ __forceinline__ float bf2f(unsigned short u) {
    return __uint_as_float((unsigned int)u << 16);
}

// packed 2x bf16 convert: D[15:0]=bf16(lo), D[31:16]=bf16(hi)
__device__ __forceinline__ unsigned int cvtpk(float lo, float hi) {
    unsigned int r;
    asm("v_cvt_pk_bf16_f32 %0, %1, %2" : "=v"(r) : "v"(lo), "v"(hi));
    return r;
}

__device__ __forceinline__ bf16x8 cvt8(float f0, float f1, float f2, float f3,
                                       float f4, float f5, float f6, float f7) {
    union { unsigned int u[4]; bf16x8 v; } r;
    r.u[0] = cvtpk(f0, f1);
    r.u[1] = cvtpk(f2, f3);
    r.u[2] = cvtpk(f4, f5);
    r.u[3] = cvtpk(f6, f7);
    return r.v;
}

// ---------------------------------------------------------------------------
// k_pre: blocks 0-50 = weight swizzle (13056 threads); blocks 51+ = grid-stride
// zero of s_agg..v_agg (N*512 floats, float4) + counts.
// ---------------------------------------------------------------------------
#define WPREP_BLOCKS 51
__global__ __launch_bounds__(256) void k_pre(
    const float* __restrict__ W1, const float* __restrict__ W2,
    const float* __restrict__ Wl2s, const float* __restrict__ Wl2v,
    const float* __restrict__ Wscs, const float* __restrict__ Wscv,
    const float* __restrict__ W0,
    const float* __restrict__ Wl1s, const float* __restrict__ Wl1v,
    unsigned short* __restrict__ w1f, unsigned short* __restrict__ w2f,
    unsigned short* __restrict__ bsf, unsigned short* __restrict__ bvf,
    unsigned short* __restrict__ w0f,
    unsigned short* __restrict__ l1sf, unsigned short* __restrict__ l1vf,
    float4* __restrict__ agg4, int* __restrict__ counts)
{
    if (blockIdx.x >= WPREP_BLOCKS) {
        int idx = (blockIdx.x - WPREP_BLOCKS) * 256 + threadIdx.x;
        int nthr = (gridDim.x - WPREP_BLOCKS) * 256;
        const size_t total4 = (size_t)N_NODES * 128;   // N*512 floats
        float4 z = {0.f, 0.f, 0.f, 0.f};
        for (size_t i = idx; i < total4; i += nthr) agg4[i] = z;
        if (idx < N_NODES) counts[idx] = 0;
        return;
    }
    int t = blockIdx.x * 256 + threadIdx.x;
    if (t < 512) {                       // W1: 8 frags (kt*4+nt)
        int f = t >> 6, lane = t & 63;
        int kt = f >> 2, nt = f & 3, q = lane >> 4, c = lane & 15;
        #pragma unroll
        for (int j = 0; j < 8; ++j) {
            int k = kt * 32 + q * 8 + j;
            int n = nt * 16 + c;
            w1f[(size_t)t * 8 + j] = f2bf(W1[k * 64 + n]);
        }
    } else if (t < 2560) {               // W2: 32 frags (kt*16+nt)
        int tt = t - 512;
        int f = tt >> 6, lane = tt & 63;
        int kt = f >> 4, nt = f & 15, q = lane >> 4, c = lane & 15;
        #pragma unroll
        for (int j = 0; j < 8; ++j) {
            int k = kt * 32 + q * 8 + j;
            int n = nt * 16 + c;
            w2f[(size_t)tt * 8 + j] = f2bf(W2[k * 256 + n]);
        }
    } else if (t < 4608) {               // bs_lin: 32 frags, 128x128
        int tt = t - 2560;
        int f = tt >> 6, lane = tt & 63;
        int kt = f >> 3, nt = f & 7, q = lane >> 4, c = lane & 15;
        #pragma unroll
        for (int j = 0; j < 8; ++j) {
            int k = kt * 32 + q * 8 + j;
            int n = nt * 16 + c;
            bsf[(size_t)tt * 8 + j] = f2bf(Wl2s[k * 128 + n] * LIN2_NORM);
        }
    } else if (t < 8704) {               // bs_sc: 64 frags (v*16+kt*8+nt), 64x128 per v
        int tt = t - 4608;
        int f = tt >> 6, lane = tt & 63;
        int v = f >> 4, g = f & 15;
        int kt = g >> 3, nt = g & 7, q = lane >> 4, c = lane & 15;
        #pragma unroll
        for (int j = 0; j < 8; ++j) {
            int u = kt * 32 + q * 8 + j;          // u < 64
            int n = nt * 16 + c;
            bsf[(size_t)(2048 + tt) * 8 + j] = f2bf(Wscs[(u * 4 + v) * 128 + n] * SC_NORM);
        }
    } else if (t < 9728) {               // bv_lin: 16 frags, 128x64
        int tt = t - 8704;
        int f = tt >> 6, lane = tt & 63;
        int kt = f >> 2, nt = f & 3, q = lane >> 4, c = lane & 15;
        #pragma unroll
        for (int j = 0; j < 8; ++j) {
            int k = kt * 32 + q * 8 + j;
            int n = nt * 16 + c;
            bvf[(size_t)tt * 8 + j] = f2bf(Wl2v[k * 64 + n] * LIN2_NORM);
        }
    } else if (t < 11776) {              // bv_sc: 32 frags (v*8+kt*4+nt), 64x64 per v
        int tt = t - 9728;
        int f = tt >> 6, lane = tt & 63;
        int v = f >> 3, g = f & 7;
        int kt = g >> 2, nt = g & 3, q = lane >> 4, c = lane & 15;
        #pragma unroll
        for (int j = 0; j < 8; ++j) {
            int u = kt * 32 + q * 8 + j;          // u < 64
            int n = nt * 16 + c;
            bvf[(size_t)(1024 + tt) * 8 + j] = f2bf(Wscv[(u * 4 + v) * 64 + n] * SC_NORM);
        }
    } else if (t < 12032) {              // w0f: 4 frags (nt), K=8 padded to 32
        int tt = t - 11776;
        int f = tt >> 6, lane = tt & 63;
        int q = lane >> 4, c = lane & 15;
        #pragma unroll
        for (int j = 0; j < 8; ++j) {
            int k = q * 8 + j;
            int n = f * 16 + c;
            w0f[(size_t)tt * 8 + j] =
                (k < 8) ? f2bf(W0[k * 64 + n] * INV_SQRT8) : (unsigned short)0;
        }
    } else if (t < 12544) {              // l1sf: 8 frags (kt*4+nt), LIN_NORM folded
        int tt = t - 12032;
        int f = tt >> 6, lane = tt & 63;
        int kt = f >> 2, nt = f & 3, q = lane >> 4, c = lane & 15;
        #pragma unroll
        for (int j = 0; j < 8; ++j) {
            int k = kt * 32 + q * 8 + j;
            int n = nt * 16 + c;
            l1sf[(size_t)tt * 8 + j] = f2bf(Wl1s[k * 64 + n] * LIN_NORM);
        }
    } else if (t < 13056) {              // l1vf: 8 frags (kt*4+nt), LIN_NORM folded
        int tt = t - 12544;
        int f = tt >> 6, lane = tt & 63;
        int kt = f >> 2, nt = f & 3, q = lane >> 4, c = lane & 15;
        #pragma unroll
        for (int j = 0; j < 8; ++j) {
            int k = kt * 32 + q * 8 + j;
            int n = nt * 16 + c;
            l1vf[(size_t)tt * 8 + j] = f2bf(Wl1v[k * 64 + n] * LIN_NORM);
        }
    }
}

// ---------------------------------------------------------------------------
// CSR build: histogram -> 1-block scan (unchanged bodies)
// ---------------------------------------------------------------------------
__global__ __launch_bounds__(256) void k_hist(const int* __restrict__ edst,
                                              int* __restrict__ counts)
{
    int e = blockIdx.x * blockDim.x + threadIdx.x;
    if (e < N_EDGES) atomicAdd(&counts[edst[e]], 1);
}

#define SCAN_T 1024
__global__ __launch_bounds__(SCAN_T) void k_scan(const int* __restrict__ counts,
                                                 int* __restrict__ cursor)
{
    __shared__ int part[SCAN_T];
    int t = threadIdx.x;
    const int CH = (N_NODES + SCAN_T - 1) / SCAN_T;   // 20
    int b0 = t * CH;
    int s = 0;
    for (int i = 0; i < CH; ++i) {
        int idx = b0 + i;
        if (idx < N_NODES) s += counts[idx];
    }
    part[t] = s;
    __syncthreads();
    for (int off = 1; off < SCAN_T; off <<= 1) {
        int v = (t >= off) ? part[t - off] : 0;
        __syncthreads();
        part[t] += v;
        __syncthreads();
    }
    int run = (t == 0) ? 0 : part[t - 1];
    for (int i = 0; i < CH; ++i) {
        int idx = b0 + i;
        if (idx < N_NODES) {
            cursor[idx] = run;
            run += counts[idx];
        }
    }
}

// ---------------------------------------------------------------------------
// k_fill_lin1: blocks 0-1249 = edge-payload scatter; blocks 1250+ = node lin1
// on MFMA (4-way wave split). lin1 now writes PACKED bf16 (s,v0,v1,v2) into
// svp: each wave writes its own 2B component of the ushort4 (no tearing).
// ---------------------------------------------------------------------------
#define FILL_BLOCKS 1250
__global__ __launch_bounds__(256) void k_fill_lin1(
    const int* __restrict__ edst, const int* __restrict__ esrc,
    const float* __restrict__ sh, const float* __restrict__ emb,
    int* __restrict__ cursor,
    int* __restrict__ dlist, int* __restrict__ slist,
    float4* __restrict__ ysort, float4* __restrict__ esort,
    const float* __restrict__ ns, const float* __restrict__ nv,
    const unsigned short* __restrict__ l1sf, const unsigned short* __restrict__ l1vf,
    unsigned short* __restrict__ svp)
{
    if (blockIdx.x < FILL_BLOCKS) {
        int e = blockIdx.x * blockDim.x + threadIdx.x;
        if (e < N_EDGES) {
            int d = edst[e];
            int pos = atomicAdd(&cursor[d], 1);
            dlist[pos] = d;
            slist[pos] = esrc[e];
            ysort[pos] = ((const float4*)sh)[e];
            esort[(size_t)pos * 2]     = ((const float4*)emb)[(size_t)e * 2];
            esort[(size_t)pos * 2 + 1] = ((const float4*)emb)[(size_t)e * 2 + 1];
        }
        return;
    }
    int lane = threadIdx.x & 63;
    int gwave = ((blockIdx.x - FILL_BLOCKS) * 256 + threadIdx.x) >> 6;
    int part = __builtin_amdgcn_readfirstlane(gwave & 3);
    int n0 = __builtin_amdgcn_readfirstlane((gwave >> 2) * 16);
    if (n0 >= N_NODES) return;
    int q = lane >> 4, c = lane & 15;
    int node = n0 + c;

    if (part == 0) {
        f32x4 Ds[4];
        #pragma unroll
        for (int nt = 0; nt < 4; ++nt) Ds[nt] = (f32x4){0.f, 0.f, 0.f, 0.f};
        #pragma unroll
        for (int kt = 0; kt < 2; ++kt) {
            const float* ap = ns + (size_t)node * 64 + kt * 32 + q * 8;
            float4 a0 = *(const float4*)ap;
            float4 a1 = *(const float4*)(ap + 4);
            bf16x8 A = cvt8(a0.x, a0.y, a0.z, a0.w, a1.x, a1.y, a1.z, a1.w);
            #pragma unroll
            for (int nt = 0; nt < 4; ++nt) {
                bf16x8 B = *(const bf16x8*)(l1sf + (size_t)((kt * 4 + nt) * 64 + lane) * 8);
                Ds[nt] = __builtin_amdgcn_mfma_f32_16x16x32_bf16(A, B, Ds[nt], 0, 0, 0);
            }
        }
        #pragma unroll
        for (int nt = 0; nt < 4; ++nt)
            #pragma unroll
            for (int r = 0; r < 4; ++r)
                svp[((size_t)(n0 + q * 4 + r) * 64 + nt * 16 + c) * 4 + 0] = f2bf(Ds[nt][r]);
    } else {
        int p = part - 1;
        f32x4 Dv[4];
        #pragma unroll
        for (int nt = 0; nt < 4; ++nt) Dv[nt] = (f32x4){0.f, 0.f, 0.f, 0.f};
        #pragma unroll
        for (int kt = 0; kt < 2; ++kt) {
            float f[8];
            #pragma unroll
            for (int j = 0; j < 8; ++j)
                f[j] = nv[(size_t)node * 192 + (size_t)(kt * 32 + q * 8 + j) * 3 + p];
            bf16x8 A = cvt8(f[0], f[1], f[2], f[3], f[4], f[5], f[6], f[7]);
            #pragma unroll
            for (int nt = 0; nt < 4; ++nt) {
                bf16x8 B = *(const bf16x8*)(l1vf + (size_t)((kt * 4 + nt) * 64 + lane) * 8);
                Dv[nt] = __builtin_amdgcn_mfma_f32_16x16x32_bf16(A, B, Dv[nt], 0, 0, 0);
            }
        }
        #pragma unroll
        for (int nt = 0; nt < 4; ++nt)
            #pragma unroll
            for (int r = 0; r < 4; ++r)
                svp[((size_t)(n0 + q * 4 + r) * 64 + nt * 16 + c) * 4 + 1 + p] = f2bf(Dv[nt][r]);
    }
}

// ---------------------------------------------------------------------------
// Kernel B (FUSED): edge MLP + TP + run-merge scatter. R13 body (aliased LDS,
// 8-edge staged scatter), with PACKED bf16 gather: one ushort4 (8B) load per
// edge-lane replaces 4 float loads (16B) — halves FETCH, quarters gather ops.
// ---------------------------------------------------------------------------
__global__ __launch_bounds__(256) void k_edge_fused(
    const float* __restrict__ esort,
    const unsigned short* __restrict__ w0f,
    const unsigned short* __restrict__ w1f, const unsigned short* __restrict__ w2f,
    const int* __restrict__ slist, const int* __restrict__ dlist,
    const float* __restrict__ ysort,
    const ushort4* __restrict__ svp,
    float* __restrict__ s_agg, float* __restrict__ v_agg)
{
    const size_t NP2 = (size_t)N_NODES * 128;

    // per-wave pool: [0,2304)=h0 | [2304,4608)=h1 | wl1 aliases [0,4224) |
    // [4608,8832)=wl2.  All sub-bases 16B-aligned (8832 = 552*16).
    __shared__ __align__(16) unsigned char pool[4 * 8832];

    int lane = threadIdx.x & 63;
    int wid  = threadIdx.x >> 6;
    int q = lane >> 4;
    int c = lane & 15;
    int lbase = __builtin_amdgcn_readfirstlane(blockIdx.x * 256 + wid * 64);
    unsigned char* base = pool + wid * 8832;
    unsigned short* myh0 = (unsigned short*)base;            // 16*72 bf16
    unsigned short* myh1 = (unsigned short*)(base + 2304);   // 16*72 bf16
    unsigned int*   myw1 = (unsigned int*)base;              // 16*66 uint (aliases h)
    unsigned int*   myw2 = (unsigned int*)(base + 4608);     // 16*66 uint

    int srcv = slist[lbase + lane];
    int dstv = dlist[lbase + lane];
    float4 y4 = ((const float4*)ysort)[lbase + lane];

    bf16x8 B0[4];
    #pragma unroll
    for (int f = 0; f < 4; ++f)
        B0[f] = *(const bf16x8*)(w0f + (size_t)(f * 64 + lane) * 8);
    bf16x8 B1[2][4];
    #pragma unroll
    for (int f = 0; f < 8; ++f)
        B1[f >> 2][f & 3] = *(const bf16x8*)(w1f + (size_t)(f * 64 + lane) * 8);

    const float4* e4 = (const float4*)esort;
    const float WS  = 0.125f * INV_NEIGH;
    const float WSD = WS * INV_SQRT3;

    float accA = 0.f, aB0 = 0.f, aB1 = 0.f, aB2 = 0.f;
    float accD = 0.f, aC0 = 0.f, aC1 = 0.f, aC2 = 0.f;
    int cur = bcast_i(dstv, 0);

    #pragma unroll 1
    for (int mt = 0; mt < 4; ++mt) {
        int tb16 = mt * 16;

        // ======== MLP phase (all MFMA, lgkm-only waits) ========
        float4 ea = {0.f, 0.f, 0.f, 0.f}, eb = {0.f, 0.f, 0.f, 0.f};
        if (q == 0) {
            ea = e4[(size_t)(lbase + tb16 + c) * 2];
            eb = e4[(size_t)(lbase + tb16 + c) * 2 + 1];
        }
        bf16x8 Ae = cvt8(ea.x, ea.y, ea.z, ea.w, eb.x, eb.y, eb.z, eb.w);
        f32x4 D0[4];
        #pragma unroll
        for (int nt = 0; nt < 4; ++nt) {
            f32x4 z = {0.f, 0.f, 0.f, 0.f};
            D0[nt] = __builtin_amdgcn_mfma_f32_16x16x32_bf16(Ae, B0[nt], z, 0, 0, 0);
        }
        #pragma unroll
        for (int nt = 0; nt < 4; ++nt)
            #pragma unroll
            for (int r = 0; r < 4; ++r)
                myh0[(q * 4 + r) * 72 + nt * 16 + c] = f2bf(silu_n(D0[nt][r]));
        __builtin_amdgcn_s_waitcnt(0xC07F);   // lgkmcnt(0) ONLY
        bf16x8 A0[2];
        #pragma unroll
        for (int kt = 0; kt < 2; ++kt)
            A0[kt] = *(const bf16x8*)(myh0 + c * 72 + kt * 32 + q * 8);

        f32x4 D1[4];
        #pragma unroll
        for (int nt = 0; nt < 4; ++nt) {
            f32x4 z = {0.f, 0.f, 0.f, 0.f};
            D1[nt] = __builtin_amdgcn_mfma_f32_16x16x32_bf16(A0[0], B1[0][nt], z, 0, 0, 0);
            D1[nt] = __builtin_amdgcn_mfma_f32_16x16x32_bf16(A0[1], B1[1][nt], D1[nt], 0, 0, 0);
        }
        #pragma unroll
        for (int nt = 0; nt < 4; ++nt)
            #pragma unroll
            for (int r = 0; r < 4; ++r)
                myh1[(q * 4 + r) * 72 + nt * 16 + c] = f2bf(silu_n(D1[nt][r] * 0.125f));
        __builtin_amdgcn_s_waitcnt(0xC07F);   // lgkmcnt(0) ONLY
        bf16x8 A1[2];
        #pragma unroll
        for (int kt = 0; kt < 2; ++kt)
            A1[kt] = *(const bf16x8*)(myh1 + c * 72 + kt * 32 + q * 8);
        // A1 now in registers: h region dead, wl1 may overwrite it.

        #pragma unroll
        for (int half = 0; half < 2; ++half) {
            int ga = half * 2, gb = half * 2 + 1;
            f32x4 Da[4], Db[4];
            #pragma unroll
            for (int ntl = 0; ntl < 4; ++ntl) {
                bf16x8 b0 = *(const bf16x8*)(w2f + (size_t)((ga * 4 + ntl) * 64 + lane) * 8);
                bf16x8 b1 = *(const bf16x8*)(w2f + (size_t)((16 + ga * 4 + ntl) * 64 + lane) * 8);
                f32x4 z = {0.f, 0.f, 0.f, 0.f};
                Da[ntl] = __builtin_amdgcn_mfma_f32_16x16x32_bf16(A1[0], b0, z, 0, 0, 0);
                Da[ntl] = __builtin_amdgcn_mfma_f32_16x16x32_bf16(A1[1], b1, Da[ntl], 0, 0, 0);
            }
            #pragma unroll
            for (int ntl = 0; ntl < 4; ++ntl) {
                bf16x8 b0 = *(const bf16x8*)(w2f + (size_t)((gb * 4 + ntl) * 64 + lane) * 8);
                bf16x8 b1 = *(const bf16x8*)(w2f + (size_t)((16 + gb * 4 + ntl) * 64 + lane) * 8);
                f32x4 z = {0.f, 0.f, 0.f, 0.f};
                Db[ntl] = __builtin_amdgcn_mfma_f32_16x16x32_bf16(A1[0], b0, z, 0, 0, 0);
                Db[ntl] = __builtin_amdgcn_mfma_f32_16x16x32_bf16(A1[1], b1, Db[ntl], 0, 0, 0);
            }
            float sb = half ? WSD : WS;
            unsigned int* pp = half ? myw2 : myw1;
            #pragma unroll
            for (int ntl = 0; ntl < 4; ++ntl)
                #pragma unroll
                for (int r = 0; r < 4; ++r)
                    pp[(q * 4 + r) * 66 + ntl * 16 + c] = cvtpk(Da[ntl][r] * WS, Db[ntl][r] * sb);
        }
        __builtin_amdgcn_s_waitcnt(0xC07F);   // drain LDS writes before reads

        // ======== scatter phase: 16 edges, staged 8 at a time, packed gather ====
        #pragma unroll 1
        for (int ebl = 0; ebl < 16; ebl += 8) {
            ushort4 sv8[8];
            unsigned int wab[8], wcd[8];
            #pragma unroll
            for (int i = 0; i < 8; ++i) {
                int et = ebl + i;                       // tile-local 0..15
                int src = bcast_i(srcv, tb16 + et);
                wab[i] = myw1[et * 66 + lane];
                wcd[i] = myw2[et * 66 + lane];
                sv8[i] = svp[(size_t)src * 64 + lane];
            }
            #pragma unroll
            for (int i = 0; i < 8; ++i) {
                int e = tb16 + ebl + i;
                int dst = bcast_i(dstv, e);
                float y0 = bcast(y4.x, e), yx = bcast(y4.y, e);
                float yy = bcast(y4.z, e), yz = bcast(y4.w, e);
                if (dst != cur) {
                    size_t db = (size_t)cur * 128;
                    unsafeAtomicAdd(&s_agg[db + lane], accA);
                    unsafeAtomicAdd(&s_agg[db + 64 + lane], accD);
                    unsafeAtomicAdd(&v_agg[0 * NP2 + db + lane], aB0);
                    unsafeAtomicAdd(&v_agg[1 * NP2 + db + lane], aB1);
                    unsafeAtomicAdd(&v_agg[2 * NP2 + db + lane], aB2);
                    unsafeAtomicAdd(&v_agg[0 * NP2 + db + 64 + lane], aC0);
                    unsafeAtomicAdd(&v_agg[1 * NP2 + db + 64 + lane], aC1);
                    unsafeAtomicAdd(&v_agg[2 * NP2 + db + 64 + lane], aC2);
                    accA = aB0 = aB1 = aB2 = 0.f;
                    accD = aC0 = aC1 = aC2 = 0.f;
                    cur = dst;
                }
                float se = bf2f(sv8[i].x);
                float v0 = bf2f(sv8[i].y);
                float v1 = bf2f(sv8[i].z);
                float v2 = bf2f(sv8[i].w);
                float wA = __uint_as_float(wab[i] << 16);
                float wB = __uint_as_float(wab[i] & 0xffff0000u);
                float wC = __uint_as_float(wcd[i] << 16);
                float wD = __uint_as_float(wcd[i] & 0xffff0000u);  // INV_SQRT3 folded
                accA = fmaf(wA, se * y0, accA);
                float bB = wB * se;
                aB0 = fmaf(bB, yx, aB0);
                aB1 = fmaf(bB, yy, aB1);
                aB2 = fmaf(bB, yz, aB2);
                float dot = v0 * yx + v1 * yy + v2 * yz;
                accD = fmaf(wD, dot, accD);
                float bC = wC * y0;
                aC0 = fmaf(bC, v0, aC0);
                aC1 = fmaf(bC, v1, aC1);
                aC2 = fmaf(bC, v2, aC2);
            }
        }
    }
    // final flush
    {
        size_t db = (size_t)cur * 128;
        unsafeAtomicAdd(&s_agg[db + lane], accA);
        unsafeAtomicAdd(&s_agg[db + 64 + lane], accD);
        unsafeAtomicAdd(&v_agg[0 * NP2 + db + lane], aB0);
        unsafeAtomicAdd(&v_agg[1 * NP2 + db + lane], aB1);
        unsafeAtomicAdd(&v_agg[2 * NP2 + db + lane], aB2);
        unsafeAtomicAdd(&v_agg[0 * NP2 + db + 64 + lane], aC0);
        unsafeAtomicAdd(&v_agg[1 * NP2 + db + 64 + lane], aC1);
        unsafeAtomicAdd(&v_agg[2 * NP2 + db + 64 + lane], aC2);
    }
}

// ---------------------------------------------------------------------------
// Kernel C1: scalar epilogue — out_s + gate -> global gbuf. (unchanged)
// ---------------------------------------------------------------------------
__global__ __launch_bounds__(256) void k_node_out_s(
    const float* __restrict__ ns, const float* __restrict__ na,
    const unsigned short* __restrict__ bsf,
    const float* __restrict__ s_agg,
    float* __restrict__ out, float* __restrict__ gbuf)
{
    int lane = threadIdx.x & 63;
    int wtile = (blockIdx.x * blockDim.x + threadIdx.x) >> 6;
    int n0 = __builtin_amdgcn_readfirstlane(wtile * 16);
    if (n0 >= N_NODES) return;
    int q = lane >> 4, c = lane & 15;
    int node = n0 + c;

    float pa[4];
    #pragma unroll
    for (int v = 0; v < 4; ++v) pa[v] = na[(size_t)node * 4 + v];

    f32x4 Ds[8];
    #pragma unroll
    for (int nt = 0; nt < 8; ++nt) Ds[nt] = (f32x4){0.f, 0.f, 0.f, 0.f};

    #pragma unroll
    for (int kt = 0; kt < 4; ++kt) {
        const float* ap = s_agg + (size_t)node * 128 + kt * 32 + q * 8;
        float4 a0 = *(const float4*)ap;
        float4 a1 = *(const float4*)(ap + 4);
        bf16x8 A;
        A[0] = (short)f2bf(a0.x); A[1] = (short)f2bf(a0.y);
        A[2] = (short)f2bf(a0.z); A[3] = (short)f2bf(a0.w);
        A[4] = (short)f2bf(a1.x); A[5] = (short)f2bf(a1.y);
        A[6] = (short)f2bf(a1.z); A[7] = (short)f2bf(a1.w);
        #pragma unroll
        for (int nt = 0; nt < 8; ++nt) {
            bf16x8 B = *(const bf16x8*)(bsf + (size_t)((kt * 8 + nt) * 64 + lane) * 8);
            Ds[nt] = __builtin_amdgcn_mfma_f32_16x16x32_bf16(A, B, Ds[nt], 0, 0, 0);
        }
    }
    {
        const float* np_ = ns + (size_t)node * 64 + q * 8;
        float4 n00 = *(const float4*)np_;
        float4 n01 = *(const float4*)(np_ + 4);
        float4 n10 = *(const float4*)(np_ + 32);
        float4 n11 = *(const float4*)(np_ + 36);
        float nsr[16] = {n00.x, n00.y, n00.z, n00.w, n01.x, n01.y, n01.z, n01.w,
                         n10.x, n10.y, n10.z, n10.w, n11.x, n11.y, n11.z, n11.w};
        #pragma unroll
        for (int v = 0; v < 4; ++v) {
            float sv = pa[v];
            #pragma unroll
            for (int kt = 0; kt < 2; ++kt) {
                bf16x8 A;
                #pragma unroll
                for (int j = 0; j < 8; ++j)
                    A[j] = (short)f2bf(nsr[kt * 8 + j] * sv);
                #pragma unroll
                for (int nt = 0; nt < 8; ++nt) {
                    bf16x8 B = *(const bf16x8*)(bsf +
                        (size_t)((32 + v * 16 + kt * 8 + nt) * 64 + lane) * 8);
                    Ds[nt] = __builtin_amdgcn_mfma_f32_16x16x32_bf16(A, B, Ds[nt], 0, 0, 0);
                }
            }
        }
    }
    #pragma unroll
    for (int nt = 0; nt < 4; ++nt)
        #pragma unroll
        for (int r = 0; r < 4; ++r) {
            out[(size_t)(n0 + q * 4 + r) * 256 + nt * 16 + c] = silu_n(Ds[nt][r]);
            gbuf[(size_t)(n0 + q * 4 + r) * 64 + nt * 16 + c] = silu_n(Ds[4 + nt][r]);
        }
}

// ---------------------------------------------------------------------------
// Kernel C2: vector epilogue — one wave per (16-node tile, p). (unchanged)
// ---------------------------------------------------------------------------
__global__ __launch_bounds__(256) void k_node_out_v(
    const float* __restrict__ nv, const float* __restrict__ na,
    const unsigned short* __restrict__ bvf,
    const float* __restrict__ v_agg, const float* __restrict__ gbuf,
    float* __restrict__ out)
{
    const size_t NP2 = (size_t)N_NODES * 128;
    int lane = threadIdx.x & 63;
    int gwave = (blockIdx.x * blockDim.x + threadIdx.x) >> 6;
    if (gwave >= 3750) return;
    int p = __builtin_amdgcn_readfirstlane(gwave % 3);
    int n0 = __builtin_amdgcn_readfirstlane((gwave / 3) * 16);
    int q = lane >> 4, c = lane & 15;
    int node = n0 + c;

    float pa[4];
    #pragma unroll
    for (int v = 0; v < 4; ++v) pa[v] = na[(size_t)node * 4 + v];

    f32x4 Dv[4];
    #pragma unroll
    for (int nt = 0; nt < 4; ++nt) Dv[nt] = (f32x4){0.f, 0.f, 0.f, 0.f};

    #pragma unroll
    for (int kt = 0; kt < 4; ++kt) {
        const float* ap = v_agg + (size_t)p * NP2 + (size_t)node * 128 + kt * 32 + q * 8;
        float4 a0 = *(const float4*)ap;
        float4 a1 = *(const float4*)(ap + 4);
        bf16x8 A;
        A[0] = (short)f2bf(a0.x); A[1] = (short)f2bf(a0.y);
        A[2] = (short)f2bf(a0.z); A[3] = (short)f2bf(a0.w);
        A[4] = (short)f2bf(a1.x); A[5] = (short)f2bf(a1.y);
        A[6] = (short)f2bf(a1.z); A[7] = (short)f2bf(a1.w);
        #pragma unroll
        for (int nt = 0; nt < 4; ++nt) {
            bf16x8 B = *(const bf16x8*)(bvf + (size_t)((kt * 4 + nt) * 64 + lane) * 8);
            Dv[nt] = __builtin_amdgcn_mfma_f32_16x16x32_bf16(A, B, Dv[nt], 0, 0, 0);
        }
    }
    float nvr[16];
    #pragma unroll
    for (int j = 0; j < 8; ++j) {
        nvr[j]     = nv[(size_t)node * 192 + (size_t)(q * 8 + j) * 3 + p];
        nvr[8 + j] = nv[(size_t)node * 192 + (size_t)(32 + q * 8 + j) * 3 + p];
    }
    #pragma unroll
    for (int v = 0; v < 4; ++v) {
        float sv = pa[v];
        #pragma unroll
        for (int kt = 0; kt < 2; ++kt) {
            bf16x8 A;
            #pragma unroll
            for (int j = 0; j < 8; ++j)
                A[j] = (short)f2bf(nvr[kt * 8 + j] * sv);
            #pragma unroll
            for (int nt = 0; nt < 4; ++nt) {
                bf16x8 B = *(const bf16x8*)(bvf +
                    (size_t)((16 + v * 8 + kt * 4 + nt) * 64 + lane) * 8);
                Dv[nt] = __builtin_amdgcn_mfma_f32_16x16x32_bf16(A, B, Dv[nt], 0, 0, 0);
            }
        }
    }
    #pragma unroll
    for (int nt = 0; nt < 4; ++nt)
        #pragma unroll
        for (int r = 0; r < 4; ++r) {
            int w = nt * 16 + c;
            float g = gbuf[(size_t)(n0 + q * 4 + r) * 64 + w];
            out[(size_t)(n0 + q * 4 + r) * 256 + 64 + (size_t)w * 3 + p] = g * Dv[nt][r];
        }
}

// ---------------------------------------------------------------------------
extern "C" void kernel_launch(void* const* d_in, const int* in_sizes, int n_in,
                              void* d_out, int out_size, void* d_ws, size_t ws_size,
                              hipStream_t stream)
{
    const float* node_scalars = (const float*)d_in[0];
    const float* node_vectors = (const float*)d_in[1];
    const float* node_attr    = (const float*)d_in[2];
    const float* edge_sh      = (const float*)d_in[3];
    const float* edge_emb     = (const float*)d_in[4];
    const int*   edge_src     = (const int*)d_in[5];
    const int*   edge_dst     = (const int*)d_in[6];
    const float* W_lin1_s = (const float*)d_in[7];
    const float* W_lin1_v = (const float*)d_in[8];
    const float* W_fc0    = (const float*)d_in[9];
    const float* W_fc1    = (const float*)d_in[10];
    const float* W_fc2    = (const float*)d_in[11];
    const float* W_lin2_s = (const float*)d_in[12];
    const float* W_lin2_v = (const float*)d_in[13];
    const float* W_sc_s   = (const float*)d_in[14];
    const float* W_sc_v   = (const float*)d_in[15];
    float* out = (float*)d_out;

    // workspace layout (all sub-arrays stay 16B-aligned)
    float* ws    = (float*)d_ws;
    float* s_agg = ws;                                    // N*128
    float* v_agg = s_agg + (size_t)N_NODES * 128;         // 3*N*128
    unsigned short* svp = (unsigned short*)(v_agg + 3 * (size_t)N_NODES * 128); // N*64*4 bf16
    float* gbuf  = (float*)(svp + (size_t)N_NODES * 256); // N*64
    int*   counts = (int*)(gbuf + (size_t)N_NODES * 64);  // N
    int*   cursor = counts + N_NODES;                     // N
    int*   dlist  = cursor + N_NODES;                     // E
    int*   slist  = dlist + N_EDGES;                      // E
    unsigned short* w1f  = (unsigned short*)(slist + N_EDGES);  // 4096
    unsigned short* w2f  = w1f + 4096;                    // 16384
    unsigned short* bsf  = w2f + 16384;                   // 49152
    unsigned short* bvf  = bsf + 49152;                   // 24576
    unsigned short* w0f  = bvf + 24576;                   // 2048
    unsigned short* l1sf = w0f + 2048;                    // 4096
    unsigned short* l1vf = l1sf + 4096;                   // 4096
    float4* ysort = (float4*)(l1vf + 4096);               // E float4
    float4* esort = ysort + N_EDGES;                      // E x 2 float4

    // D1: wprep + zero(s_agg..v_agg, counts)
    {
        k_pre<<<WPREP_BLOCKS + 2048, 256, 0, stream>>>(
            W_fc1, W_fc2, W_lin2_s, W_lin2_v, W_sc_s, W_sc_v,
            W_fc0, W_lin1_s, W_lin1_v,
            w1f, w2f, bsf, bvf, w0f, l1sf, l1vf,
            (float4*)s_agg, counts);
    }
    // D2: histogram
    {
        int blocks = (N_EDGES + 255) / 256;
        k_hist<<<blocks, 256, 0, stream>>>(edge_dst, counts);
    }
    // D3: scan
    k_scan<<<1, SCAN_T, 0, stream>>>(counts, cursor);
    // D4: fill + lin1 (independent halves, single launch; lin1 writes packed svp)
    {
        k_fill_lin1<<<FILL_BLOCKS + 1250, 256, 0, stream>>>(
            edge_dst, edge_src, edge_sh, edge_emb, cursor,
            dlist, slist, ysort, esort,
            node_scalars, node_vectors, l1sf, l1vf, svp);
    }
    // D5: fused edge pipeline (packed bf16 gather, aliased LDS)
    {
        int blocks = N_EDGES / 256;    // 1250
        k_edge_fused<<<blocks, 256, 0, stream>>>((const float*)esort, w0f, w1f, w2f,
                                                 slist, dlist, (const float*)ysort,
                                                 (const ushort4*)svp, s_agg, v_agg);
    }
    // D6: scalar epilogue (out_s + gate)
    {
        int blocks = (1250 + 3) / 4;
        k_node_out_s<<<blocks, 256, 0, stream>>>(node_scalars, node_attr, bsf,
                                                 s_agg, out, gbuf);
    }
    // D7: vector epilogue
    {
        int blocks = (3750 + 3) / 4;
        k_node_out_v<<<blocks, 256, 0, stream>>>(node_vectors, node_attr, bvf,
                                                 v_agg, gbuf, out);
    }
}